// Round 1
// 596.589 us; speedup vs baseline: 2.0284x; 2.0284x over previous
//
#include <hip/hip_runtime.h>

#define NN 50000
#define EE 400000
#define FF 128
#define NRBF 20
#define MAXDEG 64
#define NT 16
#define PI_OVER_CUT 0.6283185307179586f   // pi / 5.0

typedef _Float16 h8 __attribute__((ext_vector_type(8)));
typedef float    f4 __attribute__((ext_vector_type(4)));

// ---------------------------------------------------------------------------
__global__ __launch_bounds__(256) void k_zero(int* __restrict__ counts) {
    int i = blockIdx.x * 256 + threadIdx.x;
    if (i < NN) counts[i] = 0;
}

__global__ __launch_bounds__(256) void k_bucket(const int* __restrict__ dst,
                                                int* __restrict__ counts,
                                                int* __restrict__ slots) {
    int e = blockIdx.x * 256 + threadIdx.x;
    if (e < EE) {
        int n = dst[e];
        int slot = atomicAdd(&counts[n], 1);
        if (slot < MAXDEG) slots[n * MAXDEG + slot] = e;
    }
}

// Convert update-block weights to f16 once (L2-resident afterwards).
__global__ __launch_bounds__(256) void k_wconv(
    const float* __restrict__ Wu, const float* __restrict__ Wv,
    const float* __restrict__ Wu1, const float* __restrict__ Wu2,
    _Float16* __restrict__ Wuh, _Float16* __restrict__ Wvh,
    _Float16* __restrict__ Wu1h, _Float16* __restrict__ Wu2h)
{
    int i = blockIdx.x * 256 + threadIdx.x;
    if (i < 16384) { Wuh[i] = (_Float16)Wu[i]; Wvh[i] = (_Float16)Wv[i]; }
    if (i < 32768) { Wu1h[i] = (_Float16)Wu1[i]; }
    if (i < 49152) { Wu2h[i] = (_Float16)Wu2[i]; }
}

// ---------------------------------------------------------------------------
// K1: s0 = emb[z]; phi_s/phi_v (unchanged).
__global__ __launch_bounds__(256) void k_node_phi(
    const float* __restrict__ emb, const int* __restrict__ z,
    const float* __restrict__ Wp1, const float* __restrict__ bp1,
    const float* __restrict__ Wp2, const float* __restrict__ bp2,
    float* __restrict__ phi_s, float* __restrict__ phi_v,
    float* __restrict__ s_io)
{
    __shared__ float s_t[NT][FF];
    __shared__ float h1_t[NT][FF];
    __shared__ float wbuf[4096];
    const int t  = threadIdx.x;
    const int g0 = t & 63;
    const int h  = t >> 6;
    const int n0 = blockIdx.x * NT;

    for (int i = t; i < NT * FF; i += 256) {
        int n = i >> 7, f = i & 127;
        s_t[n][f] = emb[(size_t)z[n0 + n] * FF + f];
    }

    float acc[2][4];
    #pragma unroll
    for (int a = 0; a < 2; a++)
        #pragma unroll
        for (int i = 0; i < 4; i++) acc[a][i] = 0.f;

    for (int jt = 0; jt < 4; ++jt) {
        const int j0 = jt * 32;
        for (int r = t; r < 1024; r += 256) {
            int g = r >> 3, c4 = (r & 7) * 4;
            float4 w = *(const float4*)&Wp1[(size_t)g * FF + j0 + c4];
            wbuf[(c4 + 0) * FF + g] = w.x;
            wbuf[(c4 + 1) * FF + g] = w.y;
            wbuf[(c4 + 2) * FF + g] = w.z;
            wbuf[(c4 + 3) * FF + g] = w.w;
        }
        __syncthreads();
        for (int kk = 0; kk < 32; kk += 4) {
            float wa0 = wbuf[(kk + 0) * FF + g0], wa1 = wbuf[(kk + 1) * FF + g0];
            float wa2 = wbuf[(kk + 2) * FF + g0], wa3 = wbuf[(kk + 3) * FF + g0];
            float wb0 = wbuf[(kk + 0) * FF + g0 + 64], wb1 = wbuf[(kk + 1) * FF + g0 + 64];
            float wb2 = wbuf[(kk + 2) * FF + g0 + 64], wb3 = wbuf[(kk + 3) * FF + g0 + 64];
            #pragma unroll
            for (int i = 0; i < 4; ++i) {
                int n = h + 4 * i;
                float4 x4 = *(const float4*)&s_t[n][j0 + kk];
                acc[0][i] += wa0*x4.x + wa1*x4.y + wa2*x4.z + wa3*x4.w;
                acc[1][i] += wb0*x4.x + wb1*x4.y + wb2*x4.z + wb3*x4.w;
            }
        }
        __syncthreads();
    }
    {
        float b1a = bp1[g0], b1b = bp1[g0 + 64];
        #pragma unroll
        for (int i = 0; i < 4; i++) {
            int n = h + 4 * i;
            float xa = acc[0][i] + b1a;
            float xb = acc[1][i] + b1b;
            h1_t[n][g0]      = xa / (1.f + __expf(-xa));
            h1_t[n][g0 + 64] = xb / (1.f + __expf(-xb));
        }
    }

    float as[2][4], av[2][4];
    #pragma unroll
    for (int a = 0; a < 2; a++)
        #pragma unroll
        for (int i = 0; i < 4; i++) { as[a][i] = 0.f; av[a][i] = 0.f; }

    float* w2s = wbuf;
    float* w2v = wbuf + 2048;
    for (int jt = 0; jt < 8; ++jt) {
        const int j0 = jt * 16;
        for (int r = t; r < 512; r += 256) {
            int g = r >> 2, c4 = (r & 3) * 4;
            float4 ws4 = *(const float4*)&Wp2[(size_t)g * FF + j0 + c4];
            float4 wv4 = *(const float4*)&Wp2[(size_t)(256 + g) * FF + j0 + c4];
            w2s[(c4 + 0) * FF + g] = ws4.x;
            w2s[(c4 + 1) * FF + g] = ws4.y;
            w2s[(c4 + 2) * FF + g] = ws4.z;
            w2s[(c4 + 3) * FF + g] = ws4.w;
            w2v[(c4 + 0) * FF + g] = wv4.x;
            w2v[(c4 + 1) * FF + g] = wv4.y;
            w2v[(c4 + 2) * FF + g] = wv4.z;
            w2v[(c4 + 3) * FF + g] = wv4.w;
        }
        __syncthreads();
        for (int kk = 0; kk < 16; kk += 4) {
            float sa[4], sb[4], va[4], vb[4];
            #pragma unroll
            for (int q = 0; q < 4; ++q) {
                sa[q] = w2s[(kk + q) * FF + g0];
                sb[q] = w2s[(kk + q) * FF + g0 + 64];
                va[q] = w2v[(kk + q) * FF + g0];
                vb[q] = w2v[(kk + q) * FF + g0 + 64];
            }
            #pragma unroll
            for (int i = 0; i < 4; ++i) {
                int n = h + 4 * i;
                float4 h4 = *(const float4*)&h1_t[n][j0 + kk];
                as[0][i] += sa[0]*h4.x + sa[1]*h4.y + sa[2]*h4.z + sa[3]*h4.w;
                as[1][i] += sb[0]*h4.x + sb[1]*h4.y + sb[2]*h4.z + sb[3]*h4.w;
                av[0][i] += va[0]*h4.x + va[1]*h4.y + va[2]*h4.z + va[3]*h4.w;
                av[1][i] += vb[0]*h4.x + vb[1]*h4.y + vb[2]*h4.z + vb[3]*h4.w;
            }
        }
        __syncthreads();
    }
    {
        float bsa = bp2[g0], bsb = bp2[g0 + 64];
        float bva = bp2[256 + g0], bvb = bp2[256 + g0 + 64];
        #pragma unroll
        for (int i = 0; i < 4; i++) {
            int n = h + 4 * i;
            size_t gi = (size_t)(n0 + n) * FF;
            phi_s[gi + g0]      = as[0][i] + bsa;
            phi_s[gi + g0 + 64] = as[1][i] + bsb;
            phi_v[gi + g0]      = av[0][i] + bva;
            phi_v[gi + g0 + 64] = av[1][i] + bvb;
            s_io[gi + g0]       = s_t[n][g0];
            s_io[gi + g0 + 64]  = s_t[n][g0 + 64];
        }
    }
}

// ---------------------------------------------------------------------------
// K2: per-destination-node message accumulation. Also emits a f16 copy of v
// in [n][c][f] layout (xg) for the MFMA update kernel's A-staging.
__global__ __launch_bounds__(128) void k_edge(
    const float* __restrict__ pos,
    const float* __restrict__ Ww, const float* __restrict__ bw,
    const int* __restrict__ src,
    const int* __restrict__ counts, const int* __restrict__ slots,
    const float* __restrict__ phi_s, const float* __restrict__ phi_v,
    float* __restrict__ s_io, float* __restrict__ v_io,
    _Float16* __restrict__ xg)
{
    const int n = blockIdx.x;
    const int f = threadIdx.x;
    const int lane = threadIdx.x & 63;

    float ww_s[NRBF], ww_v[NRBF];
    #pragma unroll
    for (int k = 0; k < NRBF; k++) {
        ww_s[k] = Ww[f * NRBF + k];
        ww_v[k] = Ww[(256 + f) * NRBF + k];
    }
    const float bws = bw[f], bwv = bw[256 + f];
    const float px = pos[3 * n], py = pos[3 * n + 1], pz = pos[3 * n + 2];

    float acc_s = 0.f, av0 = 0.f, av1 = 0.f, av2 = 0.f;
    int deg = counts[n];
    deg = deg > MAXDEG ? MAXDEG : deg;

    for (int i = 0; i < deg; i++) {
        int e  = slots[n * MAXDEG + i];
        int sI = src[e];
        float rx = px - pos[3 * sI];
        float ry = py - pos[3 * sI + 1];
        float rz = pz - pos[3 * sI + 2];
        float d = sqrtf(rx * rx + ry * ry + rz * rz);
        d = fmaxf(d, 1e-9f);
        float dinv = 1.f / d;
        int kk = lane < NRBF ? lane : (NRBF - 1);
        float rbf_l = __sinf((float)(kk + 1) * PI_OVER_CUT * d) * dinv;
        int rbf_i = __float_as_int(rbf_l);
        float wfs = bws, wfv = bwv;
        #pragma unroll
        for (int k = 0; k < NRBF; k++) {
            float rk = __int_as_float(__builtin_amdgcn_readlane(rbf_i, k));
            wfs = fmaf(ww_s[k], rk, wfs);
            wfv = fmaf(ww_v[k], rk, wfv);
        }
        float sp_s = phi_s[(size_t)sI * FF + f] * wfs;
        float sp_v = phi_v[(size_t)sI * FF + f] * wfv;
        acc_s += sp_s;
        av0 = fmaf(sp_v, rx * dinv, av0);
        av1 = fmaf(sp_v, ry * dinv, av1);
        av2 = fmaf(sp_v, rz * dinv, av2);
    }
    size_t gi = (size_t)n * FF + f;
    s_io[gi] += acc_s;
    v_io[gi * 3 + 0] = av0;
    v_io[gi * 3 + 1] = av1;
    v_io[gi * 3 + 2] = av2;
    xg[((size_t)n * 3 + 0) * FF + f] = (_Float16)av0;
    xg[((size_t)n * 3 + 1) * FF + f] = (_Float16)av1;
    xg[((size_t)n * 3 + 2) * FF + f] = (_Float16)av2;
}

// ---------------------------------------------------------------------------
// K3: update block on f16 MFMA (fp32 accumulate).
// Block = 32 nodes, 4 waves. Wave w owns output features g in [32w, 32w+32)
// across all three GEMMs, so U and u.v stay in that wave's registers.
// A-operands in XOR-swizzled f16 LDS (granule ^= row&15 -> conflict-free
// ds_read_b128 fragments). B-fragments (weights) read straight from global
// (natural [g][k] rows give the 8-contiguous-k-per-lane B layout; L2-hot).
// LDS = 24 + 16 + 8 = 48 KB.
__global__ __launch_bounds__(256) void k_update_mfma(
    const _Float16* __restrict__ xg,
    const _Float16* __restrict__ Wuh, const _Float16* __restrict__ Wvh,
    const _Float16* __restrict__ Wu1h, const _Float16* __restrict__ Wu2h,
    const float* __restrict__ bu, const float* __restrict__ bv,
    const float* __restrict__ bu1, const float* __restrict__ bu2,
    float* __restrict__ s_io, float* __restrict__ v_io)
{
    __shared__ _Float16 Xs[96 * 128];    // A for GEMM1: row = c*32+n, k = f
    __shared__ _Float16 Hs[32 * 256];    // A for GEMM2: [s | Vn]
    __shared__ _Float16 H1s[32 * 128];   // A for GEMM3

    const int t    = threadIdx.x;
    const int lane = t & 63;
    const int w    = t >> 6;     // wave 0..3
    const int lr   = lane & 15;  // A-row / B-col within tile
    const int lq   = lane >> 4;  // k-chunk selector
    const int n0   = blockIdx.x * 32;
    const f4 z4 = {0.f, 0.f, 0.f, 0.f};

    // ---- stage Xs from xg (f16, coalesced 16B copies, swizzled dest) ----
    for (int i = t; i < 1536; i += 256) {            // 96 rows x 16 granules
        int row = i >> 4, gr = i & 15;
        int n = row & 31, c = row >> 5;
        int nn = n0 + n; if (nn > NN - 1) nn = NN - 1;
        uint4 d = *(const uint4*)&xg[((size_t)nn * 3 + c) * FF + gr * 8];
        *(uint4*)&Xs[(row * 16 + (gr ^ (row & 15))) * 8] = d;
    }
    // ---- stage s -> Hs[:, 0:128) ----
    for (int i = t; i < 512; i += 256) {             // 32 rows x 16 granules
        int n = i >> 4, gr = i & 15;
        int nn = n0 + n; if (nn > NN - 1) nn = NN - 1;
        const float* sp = &s_io[(size_t)nn * FF + gr * 8];
        float4 aa = *(const float4*)sp;
        float4 bb = *(const float4*)(sp + 4);
        h8 hv;
        hv[0] = (_Float16)aa.x; hv[1] = (_Float16)aa.y;
        hv[2] = (_Float16)aa.z; hv[3] = (_Float16)aa.w;
        hv[4] = (_Float16)bb.x; hv[5] = (_Float16)bb.y;
        hv[6] = (_Float16)bb.z; hv[7] = (_Float16)bb.w;
        *(h8*)&Hs[(n * 32 + (gr ^ (n & 15))) * 8] = hv;
    }
    __syncthreads();

    // ---- GEMM1: U,V[c*32+n][g] = sum_f Xs . W[g][f] ----
    f4 accU[2][6], accV[2][6];   // [g-subtile][mt = c*2+p]
    #pragma unroll
    for (int a = 0; a < 2; ++a)
        #pragma unroll
        for (int m = 0; m < 6; ++m) { accU[a][m] = z4; accV[a][m] = z4; }

    {   // U pass
        const _Float16* bb = Wuh + (size_t)lr * 128 + lq * 8;
        h8 bf[2][4];
        #pragma unroll
        for (int g2 = 0; g2 < 2; ++g2)
            #pragma unroll
            for (int ks = 0; ks < 4; ++ks)
                bf[g2][ks] = *(const h8*)(bb + ((2 * w + g2) * 16) * 128 + ks * 32);
        #pragma unroll
        for (int mt = 0; mt < 6; ++mt) {
            const int r = mt * 16 + lr;
            h8 af[4];
            #pragma unroll
            for (int ks = 0; ks < 4; ++ks)
                af[ks] = *(const h8*)&Xs[(r * 16 + ((ks * 4 + lq) ^ (r & 15))) * 8];
            #pragma unroll
            for (int g2 = 0; g2 < 2; ++g2)
                #pragma unroll
                for (int ks = 0; ks < 4; ++ks)
                    accU[g2][mt] = __builtin_amdgcn_mfma_f32_16x16x32_f16(
                        af[ks], bf[g2][ks], accU[g2][mt], 0, 0, 0);
        }
    }
    {   // V pass
        const _Float16* bb = Wvh + (size_t)lr * 128 + lq * 8;
        h8 bf[2][4];
        #pragma unroll
        for (int g2 = 0; g2 < 2; ++g2)
            #pragma unroll
            for (int ks = 0; ks < 4; ++ks)
                bf[g2][ks] = *(const h8*)(bb + ((2 * w + g2) * 16) * 128 + ks * 32);
        #pragma unroll
        for (int mt = 0; mt < 6; ++mt) {
            const int r = mt * 16 + lr;
            h8 af[4];
            #pragma unroll
            for (int ks = 0; ks < 4; ++ks)
                af[ks] = *(const h8*)&Xs[(r * 16 + ((ks * 4 + lq) ^ (r & 15))) * 8];
            #pragma unroll
            for (int g2 = 0; g2 < 2; ++g2)
                #pragma unroll
                for (int ks = 0; ks < 4; ++ks)
                    accV[g2][mt] = __builtin_amdgcn_mfma_f32_16x16x32_f16(
                        af[ks], bf[g2][ks], accV[g2][mt], 0, 0, 0);
        }
    }

    // ---- epilogue 1: bias, Vn -> Hs[:,128:256), keep U and u.v in regs ----
    float uvr[2][2][4];
    #pragma unroll
    for (int g2 = 0; g2 < 2; ++g2) {
        const int g = (2 * w + g2) * 16 + lr;
        const float bU = bu[g], bV = bv[g];
        #pragma unroll
        for (int p = 0; p < 2; ++p) {
            #pragma unroll
            for (int r = 0; r < 4; ++r) {
                float Ux = accU[g2][0 + p][r] + bU;
                float Uy = accU[g2][2 + p][r] + bU;
                float Uz = accU[g2][4 + p][r] + bU;
                float Vx = accV[g2][0 + p][r] + bV;
                float Vy = accV[g2][2 + p][r] + bV;
                float Vz = accV[g2][4 + p][r] + bV;
                accU[g2][0 + p][r] = Ux;
                accU[g2][2 + p][r] = Uy;
                accU[g2][4 + p][r] = Uz;
                uvr[g2][p][r] = Ux * Vx + Uy * Vy + Uz * Vz;
                float vn = sqrtf(Vx * Vx + Vy * Vy + Vz * Vz);
                int n = p * 16 + lq * 4 + r;
                int gr = 16 + (g >> 3);
                Hs[(n * 32 + (gr ^ (n & 15))) * 8 + (g & 7)] = (_Float16)vn;
            }
        }
    }
    __syncthreads();

    // ---- GEMM2: h1 = silu(Wu1 @ [s;Vn] + bu1) ----
    f4 acc2[2][2];
    #pragma unroll
    for (int a = 0; a < 2; ++a)
        #pragma unroll
        for (int m = 0; m < 2; ++m) acc2[a][m] = z4;
    {
        const _Float16* bb = Wu1h + (size_t)lr * 256 + lq * 8;
        #pragma unroll
        for (int g2 = 0; g2 < 2; ++g2) {
            h8 bf[8];
            #pragma unroll
            for (int ks = 0; ks < 8; ++ks)
                bf[ks] = *(const h8*)(bb + ((2 * w + g2) * 16) * 256 + ks * 32);
            #pragma unroll
            for (int mt = 0; mt < 2; ++mt) {
                const int r = mt * 16 + lr;
                #pragma unroll
                for (int ks = 0; ks < 8; ++ks) {
                    h8 af = *(const h8*)&Hs[(r * 32 + ((ks * 4 + lq) ^ (r & 15))) * 8];
                    acc2[g2][mt] = __builtin_amdgcn_mfma_f32_16x16x32_f16(
                        af, bf[ks], acc2[g2][mt], 0, 0, 0);
                }
            }
        }
    }
    #pragma unroll
    for (int g2 = 0; g2 < 2; ++g2) {
        const int g = (2 * w + g2) * 16 + lr;
        const float b1 = bu1[g];
        #pragma unroll
        for (int mt = 0; mt < 2; ++mt)
            #pragma unroll
            for (int r = 0; r < 4; ++r) {
                float x = acc2[g2][mt][r] + b1;
                float y = x / (1.f + __expf(-x));
                int n = mt * 16 + lq * 4 + r;
                int gr = g >> 3;
                H1s[(n * 16 + (gr ^ (n & 15))) * 8 + (g & 7)] = (_Float16)y;
            }
    }
    __syncthreads();

    // ---- GEMM3: a = Wu2 @ h1 + bu2 ----
    f4 acc3[3][2][2];   // [a1/a2/a3][g-subtile][p]
    #pragma unroll
    for (int a = 0; a < 3; ++a)
        #pragma unroll
        for (int b = 0; b < 2; ++b)
            #pragma unroll
            for (int m = 0; m < 2; ++m) acc3[a][b][m] = z4;
    {
        const _Float16* bb = Wu2h + (size_t)lr * 128 + lq * 8;
        #pragma unroll
        for (int ai = 0; ai < 3; ++ai)
            #pragma unroll
            for (int g2 = 0; g2 < 2; ++g2) {
                const int jt = ai * 8 + 2 * w + g2;
                h8 bf[4];
                #pragma unroll
                for (int ks = 0; ks < 4; ++ks)
                    bf[ks] = *(const h8*)(bb + (size_t)(jt * 16) * 128 + ks * 32);
                #pragma unroll
                for (int mt = 0; mt < 2; ++mt) {
                    const int r = mt * 16 + lr;
                    #pragma unroll
                    for (int ks = 0; ks < 4; ++ks) {
                        h8 af = *(const h8*)&H1s[(r * 16 + ((ks * 4 + lq) ^ (r & 15))) * 8];
                        acc3[ai][g2][mt] = __builtin_amdgcn_mfma_f32_16x16x32_f16(
                            af, bf[ks], acc3[ai][g2][mt], 0, 0, 0);
                    }
                }
            }
    }

    // ---- final epilogue: residuals from fp32 globals ----
    #pragma unroll
    for (int g2 = 0; g2 < 2; ++g2) {
        const int g = (2 * w + g2) * 16 + lr;
        const float b1 = bu2[g], b2 = bu2[128 + g], b3 = bu2[256 + g];
        #pragma unroll
        for (int p = 0; p < 2; ++p)
            #pragma unroll
            for (int r = 0; r < 4; ++r) {
                int n = p * 16 + lq * 4 + r;
                int nn = n0 + n;
                if (nn < NN) {
                    float a1 = acc3[0][g2][p][r] + b1;
                    float a2 = acc3[1][g2][p][r] + b2;
                    float a3 = acc3[2][g2][p][r] + b3;
                    size_t gi = (size_t)nn * FF + g;
                    s_io[gi] += a2 + uvr[g2][p][r] * a3;
                    v_io[gi * 3 + 0] += accU[g2][0 + p][r] * a1;
                    v_io[gi * 3 + 1] += accU[g2][2 + p][r] * a1;
                    v_io[gi * 3 + 2] += accU[g2][4 + p][r] * a1;
                }
            }
    }
}

// ---------------------------------------------------------------------------
extern "C" void kernel_launch(void* const* d_in, const int* in_sizes, int n_in,
                              void* d_out, int out_size, void* d_ws, size_t ws_size,
                              hipStream_t stream)
{
    const float* pos = (const float*)d_in[0];
    const float* emb = (const float*)d_in[1];
    const float* Wp1 = (const float*)d_in[2];
    const float* bp1 = (const float*)d_in[3];
    const float* Wp2 = (const float*)d_in[4];
    const float* bp2 = (const float*)d_in[5];
    const float* Ww  = (const float*)d_in[6];
    const float* bw  = (const float*)d_in[7];
    const float* Wu  = (const float*)d_in[8];
    const float* bu  = (const float*)d_in[9];
    const float* Wv  = (const float*)d_in[10];
    const float* bv  = (const float*)d_in[11];
    const float* Wu1 = (const float*)d_in[12];
    const float* bu1 = (const float*)d_in[13];
    const float* Wu2 = (const float*)d_in[14];
    const float* bu2 = (const float*)d_in[15];
    const int* z   = (const int*)d_in[16];
    const int* src = (const int*)d_in[17];
    const int* dst = (const int*)d_in[18];

    float* s_io = (float*)d_out;
    float* v_io = (float*)d_out + (size_t)NN * FF;

    char* ws = (char*)d_ws;
    float* phi_s = (float*)ws;
    float* phi_v = phi_s + (size_t)NN * FF;
    _Float16* xg   = (_Float16*)(phi_v + (size_t)NN * FF);
    _Float16* Wuh  = xg + (size_t)NN * 3 * FF;
    _Float16* Wvh  = Wuh + 128 * 128;
    _Float16* Wu1h = Wvh + 128 * 128;
    _Float16* Wu2h = Wu1h + 128 * 256;
    int* counts = (int*)(Wu2h + 384 * 128);
    int* slots  = counts + NN;

    k_zero  <<<(NN + 255) / 256, 256, 0, stream>>>(counts);
    k_bucket<<<(EE + 255) / 256, 256, 0, stream>>>(dst, counts, slots);
    k_wconv <<<192, 256, 0, stream>>>(Wu, Wv, Wu1, Wu2, Wuh, Wvh, Wu1h, Wu2h);
    k_node_phi<<<NN / NT, 256, 0, stream>>>(emb, z, Wp1, bp1, Wp2, bp2,
                                            phi_s, phi_v, s_io);
    k_edge<<<NN, 128, 0, stream>>>(pos, Ww, bw, src, counts, slots,
                                   phi_s, phi_v, s_io, v_io, xg);
    k_update_mfma<<<(NN + 31) / 32, 256, 0, stream>>>(xg, Wuh, Wvh, Wu1h, Wu2h,
                                                      bu, bv, bu1, bu2, s_io, v_io);
}

// Round 2
// 465.748 us; speedup vs baseline: 2.5982x; 1.2809x over previous
//
#include <hip/hip_runtime.h>

#define NN 50000
#define EE 400000
#define FF 128
#define NRBF 20
#define MAXDEG 64
#define PI_OVER_CUT 0.6283185307179586f   // pi / 5.0

typedef _Float16 h8 __attribute__((ext_vector_type(8)));
typedef float    f4 __attribute__((ext_vector_type(4)));

// ---------------------------------------------------------------------------
__global__ __launch_bounds__(256) void k_zero(int* __restrict__ counts) {
    int i = blockIdx.x * 256 + threadIdx.x;
    if (i < NN) counts[i] = 0;
}

__global__ __launch_bounds__(256) void k_bucket(const int* __restrict__ dst,
                                                int* __restrict__ counts,
                                                int* __restrict__ slots) {
    int e = blockIdx.x * 256 + threadIdx.x;
    if (e < EE) {
        int n = dst[e];
        int slot = atomicAdd(&counts[n], 1);
        if (slot < MAXDEG) slots[n * MAXDEG + slot] = e;
    }
}

// Convert all GEMM weights to f16 once (L2-resident afterwards).
__global__ __launch_bounds__(256) void k_wconv(
    const float* __restrict__ Wu, const float* __restrict__ Wv,
    const float* __restrict__ Wu1, const float* __restrict__ Wu2,
    const float* __restrict__ Wp1, const float* __restrict__ Wp2,
    _Float16* __restrict__ Wuh, _Float16* __restrict__ Wvh,
    _Float16* __restrict__ Wu1h, _Float16* __restrict__ Wu2h,
    _Float16* __restrict__ Wp1h, _Float16* __restrict__ Wp2h)
{
    int i = blockIdx.x * 256 + threadIdx.x;
    if (i < 16384) { Wuh[i] = (_Float16)Wu[i]; Wvh[i] = (_Float16)Wv[i];
                     Wp1h[i] = (_Float16)Wp1[i]; }
    if (i < 32768) { Wu1h[i] = (_Float16)Wu1[i]; }
    if (i < 49152) { Wu2h[i] = (_Float16)Wu2[i]; Wp2h[i] = (_Float16)Wp2[i]; }
}

// ---------------------------------------------------------------------------
// K1 (MFMA): s0 = emb[z]; h1 = silu(Wp1 s + bp1); phi_s/phi_v = Wp2 h1 + bp2.
// Block = 32 nodes, 4 waves; wave w owns output features g in [32w, 32w+32).
// A-operands in XOR-swizzled f16 LDS; B-fragments (weights) straight from
// global f16 (natural [g][k] rows give the MFMA B layout; L2-hot).
// phi outputs stored f16 to halve k_edge's gather traffic. LDS = 16 KB.
__global__ __launch_bounds__(256) void k_node_phi_mfma(
    const float* __restrict__ emb, const int* __restrict__ z,
    const _Float16* __restrict__ Wp1h, const float* __restrict__ bp1,
    const _Float16* __restrict__ Wp2h, const float* __restrict__ bp2,
    _Float16* __restrict__ phi_s, _Float16* __restrict__ phi_v,
    float* __restrict__ s_io)
{
    __shared__ _Float16 Ss[32 * 128];
    __shared__ _Float16 H1s[32 * 128];

    const int t    = threadIdx.x;
    const int lane = t & 63;
    const int w    = t >> 6;
    const int lr   = lane & 15;
    const int lq   = lane >> 4;
    const int n0   = blockIdx.x * 32;
    const f4 z4 = {0.f, 0.f, 0.f, 0.f};

    // ---- stage s = emb[z[n]] -> Ss (f16, swizzled) + s_io passthrough ----
    for (int i = t; i < 512; i += 256) {             // 32 rows x 16 granules
        int n = i >> 4, gr = i & 15;
        int nn = n0 + n; if (nn > NN - 1) nn = NN - 1;
        const float* sp = &emb[(size_t)z[nn] * FF + gr * 8];
        float4 aa = *(const float4*)sp;
        float4 bb = *(const float4*)(sp + 4);
        h8 hv;
        hv[0] = (_Float16)aa.x; hv[1] = (_Float16)aa.y;
        hv[2] = (_Float16)aa.z; hv[3] = (_Float16)aa.w;
        hv[4] = (_Float16)bb.x; hv[5] = (_Float16)bb.y;
        hv[6] = (_Float16)bb.z; hv[7] = (_Float16)bb.w;
        *(h8*)&Ss[(n * 16 + (gr ^ (n & 15))) * 8] = hv;
        float* op = &s_io[(size_t)nn * FF + gr * 8];
        *(float4*)op       = aa;
        *(float4*)(op + 4) = bb;
    }
    __syncthreads();

    // ---- GEMM1: h1pre[n][g] = sum_f s[n][f] * Wp1[g][f] ----
    f4 acc1[2][2];
    #pragma unroll
    for (int a = 0; a < 2; ++a)
        #pragma unroll
        for (int m = 0; m < 2; ++m) acc1[a][m] = z4;
    {
        const _Float16* bb = Wp1h + (size_t)lr * 128 + lq * 8;
        #pragma unroll
        for (int g2 = 0; g2 < 2; ++g2) {
            h8 bf[4];
            #pragma unroll
            for (int ks = 0; ks < 4; ++ks)
                bf[ks] = *(const h8*)(bb + ((2 * w + g2) * 16) * 128 + ks * 32);
            #pragma unroll
            for (int mt = 0; mt < 2; ++mt) {
                const int r = mt * 16 + lr;
                #pragma unroll
                for (int ks = 0; ks < 4; ++ks) {
                    h8 af = *(const h8*)&Ss[(r * 16 + ((ks * 4 + lq) ^ (r & 15))) * 8];
                    acc1[g2][mt] = __builtin_amdgcn_mfma_f32_16x16x32_f16(
                        af, bf[ks], acc1[g2][mt], 0, 0, 0);
                }
            }
        }
    }
    // silu -> H1s (f16, swizzled)
    #pragma unroll
    for (int g2 = 0; g2 < 2; ++g2) {
        const int g = (2 * w + g2) * 16 + lr;
        const float b1 = bp1[g];
        #pragma unroll
        for (int mt = 0; mt < 2; ++mt)
            #pragma unroll
            for (int r = 0; r < 4; ++r) {
                float x = acc1[g2][mt][r] + b1;
                float y = x / (1.f + __expf(-x));
                int n = mt * 16 + lq * 4 + r;
                H1s[(n * 16 + ((g >> 3) ^ (n & 15))) * 8 + (g & 7)] = (_Float16)y;
            }
    }
    __syncthreads();

    // ---- GEMM2: phi_s = Wp2[0:128] h1, phi_v = Wp2[256:384] h1 (shared A) ----
    f4 accS[2][2], accV[2][2];
    #pragma unroll
    for (int a = 0; a < 2; ++a)
        #pragma unroll
        for (int m = 0; m < 2; ++m) { accS[a][m] = z4; accV[a][m] = z4; }
    {
        const _Float16* bbs = Wp2h + (size_t)lr * 128 + lq * 8;
        const _Float16* bbv = Wp2h + (size_t)(256 + lr) * 128 + lq * 8;
        #pragma unroll
        for (int g2 = 0; g2 < 2; ++g2) {
            h8 bfs[4], bfv[4];
            #pragma unroll
            for (int ks = 0; ks < 4; ++ks) {
                bfs[ks] = *(const h8*)(bbs + ((2 * w + g2) * 16) * 128 + ks * 32);
                bfv[ks] = *(const h8*)(bbv + ((2 * w + g2) * 16) * 128 + ks * 32);
            }
            #pragma unroll
            for (int mt = 0; mt < 2; ++mt) {
                const int r = mt * 16 + lr;
                #pragma unroll
                for (int ks = 0; ks < 4; ++ks) {
                    h8 af = *(const h8*)&H1s[(r * 16 + ((ks * 4 + lq) ^ (r & 15))) * 8];
                    accS[g2][mt] = __builtin_amdgcn_mfma_f32_16x16x32_f16(
                        af, bfs[ks], accS[g2][mt], 0, 0, 0);
                    accV[g2][mt] = __builtin_amdgcn_mfma_f32_16x16x32_f16(
                        af, bfv[ks], accV[g2][mt], 0, 0, 0);
                }
            }
        }
    }
    // epilogue: bias + store phi (f16)
    #pragma unroll
    for (int g2 = 0; g2 < 2; ++g2) {
        const int g = (2 * w + g2) * 16 + lr;
        const float bsa = bp2[g], bva = bp2[256 + g];
        #pragma unroll
        for (int mt = 0; mt < 2; ++mt)
            #pragma unroll
            for (int r = 0; r < 4; ++r) {
                int n = mt * 16 + lq * 4 + r;
                int nn = n0 + n;
                if (nn < NN) {
                    size_t gi = (size_t)nn * FF + g;
                    phi_s[gi] = (_Float16)(accS[g2][mt][r] + bsa);
                    phi_v[gi] = (_Float16)(accV[g2][mt][r] + bva);
                }
            }
    }
}

// ---------------------------------------------------------------------------
// K2: per-destination-node message accumulation (phi gathers now f16).
__global__ __launch_bounds__(128) void k_edge(
    const float* __restrict__ pos,
    const float* __restrict__ Ww, const float* __restrict__ bw,
    const int* __restrict__ src,
    const int* __restrict__ counts, const int* __restrict__ slots,
    const _Float16* __restrict__ phi_s, const _Float16* __restrict__ phi_v,
    float* __restrict__ s_io, float* __restrict__ v_io,
    _Float16* __restrict__ xg)
{
    const int n = blockIdx.x;
    const int f = threadIdx.x;
    const int lane = threadIdx.x & 63;

    float ww_s[NRBF], ww_v[NRBF];
    #pragma unroll
    for (int k = 0; k < NRBF; k++) {
        ww_s[k] = Ww[f * NRBF + k];
        ww_v[k] = Ww[(256 + f) * NRBF + k];
    }
    const float bws = bw[f], bwv = bw[256 + f];
    const float px = pos[3 * n], py = pos[3 * n + 1], pz = pos[3 * n + 2];

    float acc_s = 0.f, av0 = 0.f, av1 = 0.f, av2 = 0.f;
    int deg = counts[n];
    deg = deg > MAXDEG ? MAXDEG : deg;

    for (int i = 0; i < deg; i++) {
        int e  = slots[n * MAXDEG + i];
        int sI = src[e];
        float rx = px - pos[3 * sI];
        float ry = py - pos[3 * sI + 1];
        float rz = pz - pos[3 * sI + 2];
        float d = sqrtf(rx * rx + ry * ry + rz * rz);
        d = fmaxf(d, 1e-9f);
        float dinv = 1.f / d;
        int kk = lane < NRBF ? lane : (NRBF - 1);
        float rbf_l = __sinf((float)(kk + 1) * PI_OVER_CUT * d) * dinv;
        int rbf_i = __float_as_int(rbf_l);
        float wfs = bws, wfv = bwv;
        #pragma unroll
        for (int k = 0; k < NRBF; k++) {
            float rk = __int_as_float(__builtin_amdgcn_readlane(rbf_i, k));
            wfs = fmaf(ww_s[k], rk, wfs);
            wfv = fmaf(ww_v[k], rk, wfv);
        }
        float sp_s = (float)phi_s[(size_t)sI * FF + f] * wfs;
        float sp_v = (float)phi_v[(size_t)sI * FF + f] * wfv;
        acc_s += sp_s;
        av0 = fmaf(sp_v, rx * dinv, av0);
        av1 = fmaf(sp_v, ry * dinv, av1);
        av2 = fmaf(sp_v, rz * dinv, av2);
    }
    size_t gi = (size_t)n * FF + f;
    s_io[gi] += acc_s;
    v_io[gi * 3 + 0] = av0;
    v_io[gi * 3 + 1] = av1;
    v_io[gi * 3 + 2] = av2;
    xg[((size_t)n * 3 + 0) * FF + f] = (_Float16)av0;
    xg[((size_t)n * 3 + 1) * FF + f] = (_Float16)av1;
    xg[((size_t)n * 3 + 2) * FF + f] = (_Float16)av2;
}

// ---------------------------------------------------------------------------
// K3: update block on f16 MFMA (fp32 accumulate) — unchanged from round 1.
__global__ __launch_bounds__(256) void k_update_mfma(
    const _Float16* __restrict__ xg,
    const _Float16* __restrict__ Wuh, const _Float16* __restrict__ Wvh,
    const _Float16* __restrict__ Wu1h, const _Float16* __restrict__ Wu2h,
    const float* __restrict__ bu, const float* __restrict__ bv,
    const float* __restrict__ bu1, const float* __restrict__ bu2,
    float* __restrict__ s_io, float* __restrict__ v_io)
{
    __shared__ _Float16 Xs[96 * 128];    // A for GEMM1: row = c*32+n, k = f
    __shared__ _Float16 Hs[32 * 256];    // A for GEMM2: [s | Vn]
    __shared__ _Float16 H1s[32 * 128];   // A for GEMM3

    const int t    = threadIdx.x;
    const int lane = t & 63;
    const int w    = t >> 6;     // wave 0..3
    const int lr   = lane & 15;  // A-row / B-col within tile
    const int lq   = lane >> 4;  // k-chunk selector
    const int n0   = blockIdx.x * 32;
    const f4 z4 = {0.f, 0.f, 0.f, 0.f};

    // ---- stage Xs from xg (f16, coalesced 16B copies, swizzled dest) ----
    for (int i = t; i < 1536; i += 256) {            // 96 rows x 16 granules
        int row = i >> 4, gr = i & 15;
        int n = row & 31, c = row >> 5;
        int nn = n0 + n; if (nn > NN - 1) nn = NN - 1;
        uint4 d = *(const uint4*)&xg[((size_t)nn * 3 + c) * FF + gr * 8];
        *(uint4*)&Xs[(row * 16 + (gr ^ (row & 15))) * 8] = d;
    }
    // ---- stage s -> Hs[:, 0:128) ----
    for (int i = t; i < 512; i += 256) {             // 32 rows x 16 granules
        int n = i >> 4, gr = i & 15;
        int nn = n0 + n; if (nn > NN - 1) nn = NN - 1;
        const float* sp = &s_io[(size_t)nn * FF + gr * 8];
        float4 aa = *(const float4*)sp;
        float4 bb = *(const float4*)(sp + 4);
        h8 hv;
        hv[0] = (_Float16)aa.x; hv[1] = (_Float16)aa.y;
        hv[2] = (_Float16)aa.z; hv[3] = (_Float16)aa.w;
        hv[4] = (_Float16)bb.x; hv[5] = (_Float16)bb.y;
        hv[6] = (_Float16)bb.z; hv[7] = (_Float16)bb.w;
        *(h8*)&Hs[(n * 32 + (gr ^ (n & 15))) * 8] = hv;
    }
    __syncthreads();

    // ---- GEMM1: U,V[c*32+n][g] = sum_f Xs . W[g][f] ----
    f4 accU[2][6], accV[2][6];   // [g-subtile][mt = c*2+p]
    #pragma unroll
    for (int a = 0; a < 2; ++a)
        #pragma unroll
        for (int m = 0; m < 6; ++m) { accU[a][m] = z4; accV[a][m] = z4; }

    {   // U pass
        const _Float16* bb = Wuh + (size_t)lr * 128 + lq * 8;
        h8 bf[2][4];
        #pragma unroll
        for (int g2 = 0; g2 < 2; ++g2)
            #pragma unroll
            for (int ks = 0; ks < 4; ++ks)
                bf[g2][ks] = *(const h8*)(bb + ((2 * w + g2) * 16) * 128 + ks * 32);
        #pragma unroll
        for (int mt = 0; mt < 6; ++mt) {
            const int r = mt * 16 + lr;
            h8 af[4];
            #pragma unroll
            for (int ks = 0; ks < 4; ++ks)
                af[ks] = *(const h8*)&Xs[(r * 16 + ((ks * 4 + lq) ^ (r & 15))) * 8];
            #pragma unroll
            for (int g2 = 0; g2 < 2; ++g2)
                #pragma unroll
                for (int ks = 0; ks < 4; ++ks)
                    accU[g2][mt] = __builtin_amdgcn_mfma_f32_16x16x32_f16(
                        af[ks], bf[g2][ks], accU[g2][mt], 0, 0, 0);
        }
    }
    {   // V pass
        const _Float16* bb = Wvh + (size_t)lr * 128 + lq * 8;
        h8 bf[2][4];
        #pragma unroll
        for (int g2 = 0; g2 < 2; ++g2)
            #pragma unroll
            for (int ks = 0; ks < 4; ++ks)
                bf[g2][ks] = *(const h8*)(bb + ((2 * w + g2) * 16) * 128 + ks * 32);
        #pragma unroll
        for (int mt = 0; mt < 6; ++mt) {
            const int r = mt * 16 + lr;
            h8 af[4];
            #pragma unroll
            for (int ks = 0; ks < 4; ++ks)
                af[ks] = *(const h8*)&Xs[(r * 16 + ((ks * 4 + lq) ^ (r & 15))) * 8];
            #pragma unroll
            for (int g2 = 0; g2 < 2; ++g2)
                #pragma unroll
                for (int ks = 0; ks < 4; ++ks)
                    accV[g2][mt] = __builtin_amdgcn_mfma_f32_16x16x32_f16(
                        af[ks], bf[g2][ks], accV[g2][mt], 0, 0, 0);
        }
    }

    // ---- epilogue 1: bias, Vn -> Hs[:,128:256), keep U and u.v in regs ----
    float uvr[2][2][4];
    #pragma unroll
    for (int g2 = 0; g2 < 2; ++g2) {
        const int g = (2 * w + g2) * 16 + lr;
        const float bU = bu[g], bV = bv[g];
        #pragma unroll
        for (int p = 0; p < 2; ++p) {
            #pragma unroll
            for (int r = 0; r < 4; ++r) {
                float Ux = accU[g2][0 + p][r] + bU;
                float Uy = accU[g2][2 + p][r] + bU;
                float Uz = accU[g2][4 + p][r] + bU;
                float Vx = accV[g2][0 + p][r] + bV;
                float Vy = accV[g2][2 + p][r] + bV;
                float Vz = accV[g2][4 + p][r] + bV;
                accU[g2][0 + p][r] = Ux;
                accU[g2][2 + p][r] = Uy;
                accU[g2][4 + p][r] = Uz;
                uvr[g2][p][r] = Ux * Vx + Uy * Vy + Uz * Vz;
                float vn = sqrtf(Vx * Vx + Vy * Vy + Vz * Vz);
                int n = p * 16 + lq * 4 + r;
                int gr = 16 + (g >> 3);
                Hs[(n * 32 + (gr ^ (n & 15))) * 8 + (g & 7)] = (_Float16)vn;
            }
        }
    }
    __syncthreads();

    // ---- GEMM2: h1 = silu(Wu1 @ [s;Vn] + bu1) ----
    f4 acc2[2][2];
    #pragma unroll
    for (int a = 0; a < 2; ++a)
        #pragma unroll
        for (int m = 0; m < 2; ++m) acc2[a][m] = z4;
    {
        const _Float16* bb = Wu1h + (size_t)lr * 256 + lq * 8;
        #pragma unroll
        for (int g2 = 0; g2 < 2; ++g2) {
            h8 bf[8];
            #pragma unroll
            for (int ks = 0; ks < 8; ++ks)
                bf[ks] = *(const h8*)(bb + ((2 * w + g2) * 16) * 256 + ks * 32);
            #pragma unroll
            for (int mt = 0; mt < 2; ++mt) {
                const int r = mt * 16 + lr;
                #pragma unroll
                for (int ks = 0; ks < 8; ++ks) {
                    h8 af = *(const h8*)&Hs[(r * 32 + ((ks * 4 + lq) ^ (r & 15))) * 8];
                    acc2[g2][mt] = __builtin_amdgcn_mfma_f32_16x16x32_f16(
                        af, bf[ks], acc2[g2][mt], 0, 0, 0);
                }
            }
        }
    }
    #pragma unroll
    for (int g2 = 0; g2 < 2; ++g2) {
        const int g = (2 * w + g2) * 16 + lr;
        const float b1 = bu1[g];
        #pragma unroll
        for (int mt = 0; mt < 2; ++mt)
            #pragma unroll
            for (int r = 0; r < 4; ++r) {
                float x = acc2[g2][mt][r] + b1;
                float y = x / (1.f + __expf(-x));
                int n = mt * 16 + lq * 4 + r;
                int gr = g >> 3;
                H1s[(n * 16 + (gr ^ (n & 15))) * 8 + (g & 7)] = (_Float16)y;
            }
    }
    __syncthreads();

    // ---- GEMM3: a = Wu2 @ h1 + bu2 ----
    f4 acc3[3][2][2];   // [a1/a2/a3][g-subtile][p]
    #pragma unroll
    for (int a = 0; a < 3; ++a)
        #pragma unroll
        for (int b = 0; b < 2; ++b)
            #pragma unroll
            for (int m = 0; m < 2; ++m) acc3[a][b][m] = z4;
    {
        const _Float16* bb = Wu2h + (size_t)lr * 128 + lq * 8;
        #pragma unroll
        for (int ai = 0; ai < 3; ++ai)
            #pragma unroll
            for (int g2 = 0; g2 < 2; ++g2) {
                const int jt = ai * 8 + 2 * w + g2;
                h8 bf[4];
                #pragma unroll
                for (int ks = 0; ks < 4; ++ks)
                    bf[ks] = *(const h8*)(bb + (size_t)(jt * 16) * 128 + ks * 32);
                #pragma unroll
                for (int mt = 0; mt < 2; ++mt) {
                    const int r = mt * 16 + lr;
                    #pragma unroll
                    for (int ks = 0; ks < 4; ++ks) {
                        h8 af = *(const h8*)&H1s[(r * 16 + ((ks * 4 + lq) ^ (r & 15))) * 8];
                        acc3[ai][g2][mt] = __builtin_amdgcn_mfma_f32_16x16x32_f16(
                            af, bf[ks], acc3[ai][g2][mt], 0, 0, 0);
                    }
                }
            }
    }

    // ---- final epilogue: residuals from fp32 globals ----
    #pragma unroll
    for (int g2 = 0; g2 < 2; ++g2) {
        const int g = (2 * w + g2) * 16 + lr;
        const float b1 = bu2[g], b2 = bu2[128 + g], b3 = bu2[256 + g];
        #pragma unroll
        for (int p = 0; p < 2; ++p)
            #pragma unroll
            for (int r = 0; r < 4; ++r) {
                int n = p * 16 + lq * 4 + r;
                int nn = n0 + n;
                if (nn < NN) {
                    float a1 = acc3[0][g2][p][r] + b1;
                    float a2 = acc3[1][g2][p][r] + b2;
                    float a3 = acc3[2][g2][p][r] + b3;
                    size_t gi = (size_t)nn * FF + g;
                    s_io[gi] += a2 + uvr[g2][p][r] * a3;
                    v_io[gi * 3 + 0] += accU[g2][0 + p][r] * a1;
                    v_io[gi * 3 + 1] += accU[g2][2 + p][r] * a1;
                    v_io[gi * 3 + 2] += accU[g2][4 + p][r] * a1;
                }
            }
    }
}

// ---------------------------------------------------------------------------
extern "C" void kernel_launch(void* const* d_in, const int* in_sizes, int n_in,
                              void* d_out, int out_size, void* d_ws, size_t ws_size,
                              hipStream_t stream)
{
    const float* pos = (const float*)d_in[0];
    const float* emb = (const float*)d_in[1];
    const float* Wp1 = (const float*)d_in[2];
    const float* bp1 = (const float*)d_in[3];
    const float* Wp2 = (const float*)d_in[4];
    const float* bp2 = (const float*)d_in[5];
    const float* Ww  = (const float*)d_in[6];
    const float* bw  = (const float*)d_in[7];
    const float* Wu  = (const float*)d_in[8];
    const float* bu  = (const float*)d_in[9];
    const float* Wv  = (const float*)d_in[10];
    const float* bv  = (const float*)d_in[11];
    const float* Wu1 = (const float*)d_in[12];
    const float* bu1 = (const float*)d_in[13];
    const float* Wu2 = (const float*)d_in[14];
    const float* bu2 = (const float*)d_in[15];
    const int* z   = (const int*)d_in[16];
    const int* src = (const int*)d_in[17];
    const int* dst = (const int*)d_in[18];

    float* s_io = (float*)d_out;
    float* v_io = (float*)d_out + (size_t)NN * FF;

    char* ws = (char*)d_ws;
    _Float16* phi_s = (_Float16*)ws;                 // NN*FF
    _Float16* phi_v = phi_s + (size_t)NN * FF;       // NN*FF
    _Float16* xg    = phi_v + (size_t)NN * FF;       // NN*3*FF
    _Float16* Wuh   = xg + (size_t)NN * 3 * FF;
    _Float16* Wvh   = Wuh  + 128 * 128;
    _Float16* Wu1h  = Wvh  + 128 * 128;
    _Float16* Wu2h  = Wu1h + 128 * 256;
    _Float16* Wp1h  = Wu2h + 384 * 128;
    _Float16* Wp2h  = Wp1h + 128 * 128;
    int* counts = (int*)(Wp2h + 384 * 128);
    int* slots  = counts + NN;

    k_zero  <<<(NN + 255) / 256, 256, 0, stream>>>(counts);
    k_bucket<<<(EE + 255) / 256, 256, 0, stream>>>(dst, counts, slots);
    k_wconv <<<192, 256, 0, stream>>>(Wu, Wv, Wu1, Wu2, Wp1, Wp2,
                                      Wuh, Wvh, Wu1h, Wu2h, Wp1h, Wp2h);
    k_node_phi_mfma<<<(NN + 31) / 32, 256, 0, stream>>>(emb, z, Wp1h, bp1,
                                                        Wp2h, bp2,
                                                        phi_s, phi_v, s_io);
    k_edge<<<NN, 128, 0, stream>>>(pos, Ww, bw, src, counts, slots,
                                   phi_s, phi_v, s_io, v_io, xg);
    k_update_mfma<<<(NN + 31) / 32, 256, 0, stream>>>(xg, Wuh, Wvh, Wu1h, Wu2h,
                                                      bu, bv, bu1, bu2, s_io, v_io);
}

// Round 3
// 424.944 us; speedup vs baseline: 2.8477x; 1.0960x over previous
//
#include <hip/hip_runtime.h>

#define NN 50000
#define EE 400000
#define FF 128
#define NRBF 20
#define MAXDEG 64
#define PI_OVER_CUT 0.6283185307179586f   // pi / 5.0

typedef _Float16 h8 __attribute__((ext_vector_type(8)));
typedef float    f4 __attribute__((ext_vector_type(4)));

union pk32 { unsigned int u; _Float16 h[2]; };

// ---------------------------------------------------------------------------
__global__ __launch_bounds__(256) void k_zero(int* __restrict__ counts) {
    int i = blockIdx.x * 256 + threadIdx.x;
    if (i < NN) counts[i] = 0;
}

__global__ __launch_bounds__(256) void k_bucket(const int* __restrict__ dst,
                                                int* __restrict__ counts,
                                                int* __restrict__ slots) {
    int e = blockIdx.x * 256 + threadIdx.x;
    if (e < EE) {
        int n = dst[e];
        int slot = atomicAdd(&counts[n], 1);
        if (slot < MAXDEG) slots[n * MAXDEG + slot] = e;
    }
}

// Convert all GEMM weights to f16 once (L2-resident afterwards).
// Wwh32: [256 cols][32 k] where cols 0:128 = Ww rows 0:128 (s-gate),
// cols 128:256 = Ww rows 256:384 (vector-gate); k=20 column holds the bias
// (paired with a constant-1 rbf element), k=21..31 are zero (pad).
__global__ __launch_bounds__(256) void k_wconv(
    const float* __restrict__ Wu, const float* __restrict__ Wv,
    const float* __restrict__ Wu1, const float* __restrict__ Wu2,
    const float* __restrict__ Wp1, const float* __restrict__ Wp2,
    const float* __restrict__ Ww, const float* __restrict__ bw,
    _Float16* __restrict__ Wuh, _Float16* __restrict__ Wvh,
    _Float16* __restrict__ Wu1h, _Float16* __restrict__ Wu2h,
    _Float16* __restrict__ Wp1h, _Float16* __restrict__ Wp2h,
    _Float16* __restrict__ Wwh32)
{
    int i = blockIdx.x * 256 + threadIdx.x;
    if (i < 16384) { Wuh[i] = (_Float16)Wu[i]; Wvh[i] = (_Float16)Wv[i];
                     Wp1h[i] = (_Float16)Wp1[i]; }
    if (i < 32768) { Wu1h[i] = (_Float16)Wu1[i]; }
    if (i < 49152) { Wu2h[i] = (_Float16)Wu2[i]; Wp2h[i] = (_Float16)Wp2[i]; }
    if (i < 8192) {
        int col = i >> 5, k = i & 31;
        int sr = col < 128 ? col : col + 128;
        _Float16 v = (_Float16)0.f;
        if (k < 20)       v = (_Float16)Ww[sr * NRBF + k];
        else if (k == 20) v = (_Float16)bw[sr];
        Wwh32[i] = v;
    }
}

// ---------------------------------------------------------------------------
// K1 (MFMA): s0 = emb[z]; h1 = silu(Wp1 s + bp1); phi = Wp2 h1 + bp2.
// phi_s/phi_v stored interleaved f16 pairs (one uint per (n,f)).
__global__ __launch_bounds__(256) void k_node_phi_mfma(
    const float* __restrict__ emb, const int* __restrict__ z,
    const _Float16* __restrict__ Wp1h, const float* __restrict__ bp1,
    const _Float16* __restrict__ Wp2h, const float* __restrict__ bp2,
    unsigned int* __restrict__ phi_pk, float* __restrict__ s_io)
{
    __shared__ _Float16 Ss[32 * 128];
    __shared__ _Float16 H1s[32 * 128];

    const int t    = threadIdx.x;
    const int lane = t & 63;
    const int w    = t >> 6;
    const int lr   = lane & 15;
    const int lq   = lane >> 4;
    const int n0   = blockIdx.x * 32;
    const f4 z4 = {0.f, 0.f, 0.f, 0.f};

    for (int i = t; i < 512; i += 256) {             // 32 rows x 16 granules
        int n = i >> 4, gr = i & 15;
        int nn = n0 + n; if (nn > NN - 1) nn = NN - 1;
        const float* sp = &emb[(size_t)z[nn] * FF + gr * 8];
        float4 aa = *(const float4*)sp;
        float4 bb = *(const float4*)(sp + 4);
        h8 hv;
        hv[0] = (_Float16)aa.x; hv[1] = (_Float16)aa.y;
        hv[2] = (_Float16)aa.z; hv[3] = (_Float16)aa.w;
        hv[4] = (_Float16)bb.x; hv[5] = (_Float16)bb.y;
        hv[6] = (_Float16)bb.z; hv[7] = (_Float16)bb.w;
        *(h8*)&Ss[(n * 16 + (gr ^ (n & 15))) * 8] = hv;
        float* op = &s_io[(size_t)nn * FF + gr * 8];
        *(float4*)op       = aa;
        *(float4*)(op + 4) = bb;
    }
    __syncthreads();

    f4 acc1[2][2];
    #pragma unroll
    for (int a = 0; a < 2; ++a)
        #pragma unroll
        for (int m = 0; m < 2; ++m) acc1[a][m] = z4;
    {
        const _Float16* bb = Wp1h + (size_t)lr * 128 + lq * 8;
        #pragma unroll
        for (int g2 = 0; g2 < 2; ++g2) {
            h8 bf[4];
            #pragma unroll
            for (int ks = 0; ks < 4; ++ks)
                bf[ks] = *(const h8*)(bb + ((2 * w + g2) * 16) * 128 + ks * 32);
            #pragma unroll
            for (int mt = 0; mt < 2; ++mt) {
                const int r = mt * 16 + lr;
                #pragma unroll
                for (int ks = 0; ks < 4; ++ks) {
                    h8 af = *(const h8*)&Ss[(r * 16 + ((ks * 4 + lq) ^ (r & 15))) * 8];
                    acc1[g2][mt] = __builtin_amdgcn_mfma_f32_16x16x32_f16(
                        af, bf[ks], acc1[g2][mt], 0, 0, 0);
                }
            }
        }
    }
    #pragma unroll
    for (int g2 = 0; g2 < 2; ++g2) {
        const int g = (2 * w + g2) * 16 + lr;
        const float b1 = bp1[g];
        #pragma unroll
        for (int mt = 0; mt < 2; ++mt)
            #pragma unroll
            for (int r = 0; r < 4; ++r) {
                float x = acc1[g2][mt][r] + b1;
                float y = x / (1.f + __expf(-x));
                int n = mt * 16 + lq * 4 + r;
                H1s[(n * 16 + ((g >> 3) ^ (n & 15))) * 8 + (g & 7)] = (_Float16)y;
            }
    }
    __syncthreads();

    f4 accS[2][2], accV[2][2];
    #pragma unroll
    for (int a = 0; a < 2; ++a)
        #pragma unroll
        for (int m = 0; m < 2; ++m) { accS[a][m] = z4; accV[a][m] = z4; }
    {
        const _Float16* bbs = Wp2h + (size_t)lr * 128 + lq * 8;
        const _Float16* bbv = Wp2h + (size_t)(256 + lr) * 128 + lq * 8;
        #pragma unroll
        for (int g2 = 0; g2 < 2; ++g2) {
            h8 bfs[4], bfv[4];
            #pragma unroll
            for (int ks = 0; ks < 4; ++ks) {
                bfs[ks] = *(const h8*)(bbs + ((2 * w + g2) * 16) * 128 + ks * 32);
                bfv[ks] = *(const h8*)(bbv + ((2 * w + g2) * 16) * 128 + ks * 32);
            }
            #pragma unroll
            for (int mt = 0; mt < 2; ++mt) {
                const int r = mt * 16 + lr;
                #pragma unroll
                for (int ks = 0; ks < 4; ++ks) {
                    h8 af = *(const h8*)&H1s[(r * 16 + ((ks * 4 + lq) ^ (r & 15))) * 8];
                    accS[g2][mt] = __builtin_amdgcn_mfma_f32_16x16x32_f16(
                        af, bfs[ks], accS[g2][mt], 0, 0, 0);
                    accV[g2][mt] = __builtin_amdgcn_mfma_f32_16x16x32_f16(
                        af, bfv[ks], accV[g2][mt], 0, 0, 0);
                }
            }
        }
    }
    #pragma unroll
    for (int g2 = 0; g2 < 2; ++g2) {
        const int g = (2 * w + g2) * 16 + lr;
        const float bsa = bp2[g], bva = bp2[256 + g];
        #pragma unroll
        for (int mt = 0; mt < 2; ++mt)
            #pragma unroll
            for (int r = 0; r < 4; ++r) {
                int n = mt * 16 + lq * 4 + r;
                int nn = n0 + n;
                if (nn < NN) {
                    pk32 pk;
                    pk.h[0] = (_Float16)(accS[g2][mt][r] + bsa);
                    pk.h[1] = (_Float16)(accV[g2][mt][r] + bva);
                    phi_pk[(size_t)nn * FF + g] = pk.u;
                }
            }
    }
}

// ---------------------------------------------------------------------------
// K2 (MFMA Wf): per destination node. Batches <=16 edges into an A-tile of
// rbf values (K padded to 32; k=20 is a constant-1 "bias" element) and
// computes Wf[16][256] = rbf @ Wwh32^T via 8 MFMA/wave. Accumulation loop is
// then ~13 VALU issues per edge instead of ~150.
__global__ __launch_bounds__(128) void k_edge_mfma(
    const float* __restrict__ pos,
    const _Float16* __restrict__ Wwh32,
    const int* __restrict__ src,
    const int* __restrict__ counts, const int* __restrict__ slots,
    const unsigned int* __restrict__ phi_pk,
    float* __restrict__ s_io, float* __restrict__ v_io,
    _Float16* __restrict__ xg)
{
    __shared__ _Float16 A[16 * 32];          // swizzled rbf A-tile (1 KB)
    __shared__ float dirs[16][4];            // ux, uy, uz, asfloat(sI)
    __shared__ float dls[16];                // distance per edge
    __shared__ unsigned int wf[16 * 130];    // interleaved {s,v} f16 Wf (8.3 KB)

    const int t    = threadIdx.x;
    const int lane = t & 63;
    const int w    = t >> 6;     // wave 0 = s-half, wave 1 = v-half
    const int lr   = lane & 15;
    const int lq   = lane >> 4;
    const int n    = blockIdx.x;
    const f4 z4 = {0.f, 0.f, 0.f, 0.f};

    // B-fragments: tile-invariant, loaded once (L2-hot).
    h8 bf[8];
    #pragma unroll
    for (int j = 0; j < 8; ++j)
        bf[j] = *(const h8*)&Wwh32[(size_t)((w * 8 + j) * 16 + lr) * 32 + lq * 8];

    const float px = pos[3 * n], py = pos[3 * n + 1], pz = pos[3 * n + 2];

    int deg = counts[n];
    deg = deg > MAXDEG ? MAXDEG : deg;

    float acc_s = 0.f, av0 = 0.f, av1 = 0.f, av2 = 0.f;

    for (int t0 = 0; t0 < deg; t0 += 16) {
        const int degT = (deg - t0) < 16 ? (deg - t0) : 16;
        __syncthreads();                       // guard LDS reuse
        // ---- phase 1: per-edge geometry (threads 0..degT-1) ----
        if (t < degT) {
            int e  = slots[n * MAXDEG + t0 + t];
            int sI = src[e];
            float rx = px - pos[3 * sI];
            float ry = py - pos[3 * sI + 1];
            float rz = pz - pos[3 * sI + 2];
            float d = sqrtf(rx * rx + ry * ry + rz * rz);
            d = fmaxf(d, 1e-9f);
            float di = 1.f / d;
            dirs[t][0] = rx * di;
            dirs[t][1] = ry * di;
            dirs[t][2] = rz * di;
            dirs[t][3] = __int_as_float(sI);
            dls[t] = d;
        }
        __syncthreads();
        // ---- phase 2: rbf -> A-tile. thread = (edge m = t&15, kk = t>>4) ----
        {
            const int m = t & 15, kk = t >> 4;
            float d  = dls[m];
            float di = 1.f / d;
            float v0 = __sinf((float)(kk + 1) * PI_OVER_CUT * d) * di;
            float v1 = __sinf((float)(kk + 9) * PI_OVER_CUT * d) * di;
            float v2;
            if (kk < 4)       v2 = __sinf((float)(kk + 17) * PI_OVER_CUT * d) * di;
            else if (kk == 4) v2 = 1.0f;     // k=20: bias element
            else              v2 = 0.f;
            // chunk-swizzled store: phys chunk = (k>>3) ^ (m&3)
            #define STO(K, V) A[m * 32 + (((K) >> 3) ^ (m & 3)) * 8 + ((K) & 7)] = (_Float16)(V)
            STO(kk,      v0);
            STO(kk + 8,  v1);
            STO(kk + 16, v2);
            STO(kk + 24, 0.f);
            #undef STO
        }
        __syncthreads();
        // ---- MFMA: Wf tile (each wave: 8 n-tiles of 16 features) ----
        {
            h8 af = *(const h8*)&A[(lr * 4 + (lq ^ (lr & 3))) * 8];
            #pragma unroll
            for (int j = 0; j < 8; ++j) {
                f4 dd = __builtin_amdgcn_mfma_f32_16x16x32_f16(af, bf[j], z4, 0, 0, 0);
                #pragma unroll
                for (int r = 0; r < 4; ++r) {
                    int m = lq * 4 + r;
                    ((_Float16*)&wf[m * 130 + j * 16 + lr])[w] = (_Float16)dd[r];
                }
            }
        }
        __syncthreads();
        // ---- accumulation over this tile's edges ----
        for (int m = 0; m < degT; ++m) {
            float4 dir = *(const float4*)&dirs[m][0];
            int sI = __builtin_amdgcn_readfirstlane(__float_as_int(dir.w));
            pk32 ph, wfu;
            ph.u  = phi_pk[(size_t)sI * FF + t];
            wfu.u = wf[m * 130 + t];
            float ps = (float)ph.h[0] * (float)wfu.h[0];
            float pv = (float)ph.h[1] * (float)wfu.h[1];
            acc_s += ps;
            av0 = fmaf(pv, dir.x, av0);
            av1 = fmaf(pv, dir.y, av1);
            av2 = fmaf(pv, dir.z, av2);
        }
    }

    size_t gi = (size_t)n * FF + t;
    s_io[gi] += acc_s;
    v_io[gi * 3 + 0] = av0;
    v_io[gi * 3 + 1] = av1;
    v_io[gi * 3 + 2] = av2;
    xg[((size_t)n * 3 + 0) * FF + t] = (_Float16)av0;
    xg[((size_t)n * 3 + 1) * FF + t] = (_Float16)av1;
    xg[((size_t)n * 3 + 2) * FF + t] = (_Float16)av2;
}

// ---------------------------------------------------------------------------
// K3: update block on f16 MFMA (fp32 accumulate) — unchanged.
__global__ __launch_bounds__(256) void k_update_mfma(
    const _Float16* __restrict__ xg,
    const _Float16* __restrict__ Wuh, const _Float16* __restrict__ Wvh,
    const _Float16* __restrict__ Wu1h, const _Float16* __restrict__ Wu2h,
    const float* __restrict__ bu, const float* __restrict__ bv,
    const float* __restrict__ bu1, const float* __restrict__ bu2,
    float* __restrict__ s_io, float* __restrict__ v_io)
{
    __shared__ _Float16 Xs[96 * 128];    // A for GEMM1: row = c*32+n, k = f
    __shared__ _Float16 Hs[32 * 256];    // A for GEMM2: [s | Vn]
    __shared__ _Float16 H1s[32 * 128];   // A for GEMM3

    const int t    = threadIdx.x;
    const int lane = t & 63;
    const int w    = t >> 6;     // wave 0..3
    const int lr   = lane & 15;  // A-row / B-col within tile
    const int lq   = lane >> 4;  // k-chunk selector
    const int n0   = blockIdx.x * 32;
    const f4 z4 = {0.f, 0.f, 0.f, 0.f};

    for (int i = t; i < 1536; i += 256) {            // 96 rows x 16 granules
        int row = i >> 4, gr = i & 15;
        int n = row & 31, c = row >> 5;
        int nn = n0 + n; if (nn > NN - 1) nn = NN - 1;
        uint4 d = *(const uint4*)&xg[((size_t)nn * 3 + c) * FF + gr * 8];
        *(uint4*)&Xs[(row * 16 + (gr ^ (row & 15))) * 8] = d;
    }
    for (int i = t; i < 512; i += 256) {             // 32 rows x 16 granules
        int n = i >> 4, gr = i & 15;
        int nn = n0 + n; if (nn > NN - 1) nn = NN - 1;
        const float* sp = &s_io[(size_t)nn * FF + gr * 8];
        float4 aa = *(const float4*)sp;
        float4 bb = *(const float4*)(sp + 4);
        h8 hv;
        hv[0] = (_Float16)aa.x; hv[1] = (_Float16)aa.y;
        hv[2] = (_Float16)aa.z; hv[3] = (_Float16)aa.w;
        hv[4] = (_Float16)bb.x; hv[5] = (_Float16)bb.y;
        hv[6] = (_Float16)bb.z; hv[7] = (_Float16)bb.w;
        *(h8*)&Hs[(n * 32 + (gr ^ (n & 15))) * 8] = hv;
    }
    __syncthreads();

    f4 accU[2][6], accV[2][6];   // [g-subtile][mt = c*2+p]
    #pragma unroll
    for (int a = 0; a < 2; ++a)
        #pragma unroll
        for (int m = 0; m < 6; ++m) { accU[a][m] = z4; accV[a][m] = z4; }

    {   // U pass
        const _Float16* bb = Wuh + (size_t)lr * 128 + lq * 8;
        h8 bfr[2][4];
        #pragma unroll
        for (int g2 = 0; g2 < 2; ++g2)
            #pragma unroll
            for (int ks = 0; ks < 4; ++ks)
                bfr[g2][ks] = *(const h8*)(bb + ((2 * w + g2) * 16) * 128 + ks * 32);
        #pragma unroll
        for (int mt = 0; mt < 6; ++mt) {
            const int r = mt * 16 + lr;
            h8 af[4];
            #pragma unroll
            for (int ks = 0; ks < 4; ++ks)
                af[ks] = *(const h8*)&Xs[(r * 16 + ((ks * 4 + lq) ^ (r & 15))) * 8];
            #pragma unroll
            for (int g2 = 0; g2 < 2; ++g2)
                #pragma unroll
                for (int ks = 0; ks < 4; ++ks)
                    accU[g2][mt] = __builtin_amdgcn_mfma_f32_16x16x32_f16(
                        af[ks], bfr[g2][ks], accU[g2][mt], 0, 0, 0);
        }
    }
    {   // V pass
        const _Float16* bb = Wvh + (size_t)lr * 128 + lq * 8;
        h8 bfr[2][4];
        #pragma unroll
        for (int g2 = 0; g2 < 2; ++g2)
            #pragma unroll
            for (int ks = 0; ks < 4; ++ks)
                bfr[g2][ks] = *(const h8*)(bb + ((2 * w + g2) * 16) * 128 + ks * 32);
        #pragma unroll
        for (int mt = 0; mt < 6; ++mt) {
            const int r = mt * 16 + lr;
            h8 af[4];
            #pragma unroll
            for (int ks = 0; ks < 4; ++ks)
                af[ks] = *(const h8*)&Xs[(r * 16 + ((ks * 4 + lq) ^ (r & 15))) * 8];
            #pragma unroll
            for (int g2 = 0; g2 < 2; ++g2)
                #pragma unroll
                for (int ks = 0; ks < 4; ++ks)
                    accV[g2][mt] = __builtin_amdgcn_mfma_f32_16x16x32_f16(
                        af[ks], bfr[g2][ks], accV[g2][mt], 0, 0, 0);
        }
    }

    float uvr[2][2][4];
    #pragma unroll
    for (int g2 = 0; g2 < 2; ++g2) {
        const int g = (2 * w + g2) * 16 + lr;
        const float bU = bu[g], bV = bv[g];
        #pragma unroll
        for (int p = 0; p < 2; ++p) {
            #pragma unroll
            for (int r = 0; r < 4; ++r) {
                float Ux = accU[g2][0 + p][r] + bU;
                float Uy = accU[g2][2 + p][r] + bU;
                float Uz = accU[g2][4 + p][r] + bU;
                float Vx = accV[g2][0 + p][r] + bV;
                float Vy = accV[g2][2 + p][r] + bV;
                float Vz = accV[g2][4 + p][r] + bV;
                accU[g2][0 + p][r] = Ux;
                accU[g2][2 + p][r] = Uy;
                accU[g2][4 + p][r] = Uz;
                uvr[g2][p][r] = Ux * Vx + Uy * Vy + Uz * Vz;
                float vn = sqrtf(Vx * Vx + Vy * Vy + Vz * Vz);
                int n = p * 16 + lq * 4 + r;
                int gr = 16 + (g >> 3);
                Hs[(n * 32 + (gr ^ (n & 15))) * 8 + (g & 7)] = (_Float16)vn;
            }
        }
    }
    __syncthreads();

    f4 acc2[2][2];
    #pragma unroll
    for (int a = 0; a < 2; ++a)
        #pragma unroll
        for (int m = 0; m < 2; ++m) acc2[a][m] = z4;
    {
        const _Float16* bb = Wu1h + (size_t)lr * 256 + lq * 8;
        #pragma unroll
        for (int g2 = 0; g2 < 2; ++g2) {
            h8 bfr[8];
            #pragma unroll
            for (int ks = 0; ks < 8; ++ks)
                bfr[ks] = *(const h8*)(bb + ((2 * w + g2) * 16) * 256 + ks * 32);
            #pragma unroll
            for (int mt = 0; mt < 2; ++mt) {
                const int r = mt * 16 + lr;
                #pragma unroll
                for (int ks = 0; ks < 8; ++ks) {
                    h8 af = *(const h8*)&Hs[(r * 32 + ((ks * 4 + lq) ^ (r & 15))) * 8];
                    acc2[g2][mt] = __builtin_amdgcn_mfma_f32_16x16x32_f16(
                        af, bfr[ks], acc2[g2][mt], 0, 0, 0);
                }
            }
        }
    }
    #pragma unroll
    for (int g2 = 0; g2 < 2; ++g2) {
        const int g = (2 * w + g2) * 16 + lr;
        const float b1 = bu1[g];
        #pragma unroll
        for (int mt = 0; mt < 2; ++mt)
            #pragma unroll
            for (int r = 0; r < 4; ++r) {
                float x = acc2[g2][mt][r] + b1;
                float y = x / (1.f + __expf(-x));
                int n = mt * 16 + lq * 4 + r;
                int gr = g >> 3;
                H1s[(n * 16 + (gr ^ (n & 15))) * 8 + (g & 7)] = (_Float16)y;
            }
    }
    __syncthreads();

    f4 acc3[3][2][2];
    #pragma unroll
    for (int a = 0; a < 3; ++a)
        #pragma unroll
        for (int b = 0; b < 2; ++b)
            #pragma unroll
            for (int m = 0; m < 2; ++m) acc3[a][b][m] = z4;
    {
        const _Float16* bb = Wu2h + (size_t)lr * 128 + lq * 8;
        #pragma unroll
        for (int ai = 0; ai < 3; ++ai)
            #pragma unroll
            for (int g2 = 0; g2 < 2; ++g2) {
                const int jt = ai * 8 + 2 * w + g2;
                h8 bfr[4];
                #pragma unroll
                for (int ks = 0; ks < 4; ++ks)
                    bfr[ks] = *(const h8*)(bb + (size_t)(jt * 16) * 128 + ks * 32);
                #pragma unroll
                for (int mt = 0; mt < 2; ++mt) {
                    const int r = mt * 16 + lr;
                    #pragma unroll
                    for (int ks = 0; ks < 4; ++ks) {
                        h8 af = *(const h8*)&H1s[(r * 16 + ((ks * 4 + lq) ^ (r & 15))) * 8];
                        acc3[ai][g2][mt] = __builtin_amdgcn_mfma_f32_16x16x32_f16(
                            af, bfr[ks], acc3[ai][g2][mt], 0, 0, 0);
                    }
                }
            }
    }

    #pragma unroll
    for (int g2 = 0; g2 < 2; ++g2) {
        const int g = (2 * w + g2) * 16 + lr;
        const float b1 = bu2[g], b2 = bu2[128 + g], b3 = bu2[256 + g];
        #pragma unroll
        for (int p = 0; p < 2; ++p)
            #pragma unroll
            for (int r = 0; r < 4; ++r) {
                int n = p * 16 + lq * 4 + r;
                int nn = n0 + n;
                if (nn < NN) {
                    float a1 = acc3[0][g2][p][r] + b1;
                    float a2 = acc3[1][g2][p][r] + b2;
                    float a3 = acc3[2][g2][p][r] + b3;
                    size_t gi = (size_t)nn * FF + g;
                    s_io[gi] += a2 + uvr[g2][p][r] * a3;
                    v_io[gi * 3 + 0] += accU[g2][0 + p][r] * a1;
                    v_io[gi * 3 + 1] += accU[g2][2 + p][r] * a1;
                    v_io[gi * 3 + 2] += accU[g2][4 + p][r] * a1;
                }
            }
    }
}

// ---------------------------------------------------------------------------
extern "C" void kernel_launch(void* const* d_in, const int* in_sizes, int n_in,
                              void* d_out, int out_size, void* d_ws, size_t ws_size,
                              hipStream_t stream)
{
    const float* pos = (const float*)d_in[0];
    const float* emb = (const float*)d_in[1];
    const float* Wp1 = (const float*)d_in[2];
    const float* bp1 = (const float*)d_in[3];
    const float* Wp2 = (const float*)d_in[4];
    const float* bp2 = (const float*)d_in[5];
    const float* Ww  = (const float*)d_in[6];
    const float* bw  = (const float*)d_in[7];
    const float* Wu  = (const float*)d_in[8];
    const float* bu  = (const float*)d_in[9];
    const float* Wv  = (const float*)d_in[10];
    const float* bv  = (const float*)d_in[11];
    const float* Wu1 = (const float*)d_in[12];
    const float* bu1 = (const float*)d_in[13];
    const float* Wu2 = (const float*)d_in[14];
    const float* bu2 = (const float*)d_in[15];
    const int* z   = (const int*)d_in[16];
    const int* src = (const int*)d_in[17];
    const int* dst = (const int*)d_in[18];

    float* s_io = (float*)d_out;
    float* v_io = (float*)d_out + (size_t)NN * FF;

    char* ws = (char*)d_ws;
    unsigned int* phi_pk = (unsigned int*)ws;            // NN*FF uints
    _Float16* xg    = (_Float16*)(phi_pk + (size_t)NN * FF);  // NN*3*FF
    _Float16* Wuh   = xg + (size_t)NN * 3 * FF;
    _Float16* Wvh   = Wuh  + 128 * 128;
    _Float16* Wu1h  = Wvh  + 128 * 128;
    _Float16* Wu2h  = Wu1h + 128 * 256;
    _Float16* Wp1h  = Wu2h + 384 * 128;
    _Float16* Wp2h  = Wp1h + 128 * 128;
    _Float16* Wwh32 = Wp2h + 384 * 128;                  // 256*32
    int* counts = (int*)(Wwh32 + 256 * 32);
    int* slots  = counts + NN;

    k_zero  <<<(NN + 255) / 256, 256, 0, stream>>>(counts);
    k_bucket<<<(EE + 255) / 256, 256, 0, stream>>>(dst, counts, slots);
    k_wconv <<<192, 256, 0, stream>>>(Wu, Wv, Wu1, Wu2, Wp1, Wp2, Ww, bw,
                                      Wuh, Wvh, Wu1h, Wu2h, Wp1h, Wp2h, Wwh32);
    k_node_phi_mfma<<<(NN + 31) / 32, 256, 0, stream>>>(emb, z, Wp1h, bp1,
                                                        Wp2h, bp2,
                                                        phi_pk, s_io);
    k_edge_mfma<<<NN, 128, 0, stream>>>(pos, Wwh32, src, counts, slots,
                                        phi_pk, s_io, v_io, xg);
    k_update_mfma<<<(NN + 31) / 32, 256, 0, stream>>>(xg, Wuh, Wvh, Wu1h, Wu2h,
                                                      bu, bv, bu1, bu2, s_io, v_io);
}

// Round 4
// 396.070 us; speedup vs baseline: 3.0553x; 1.0729x over previous
//
#include <hip/hip_runtime.h>

#define NN 50000
#define EE 400000
#define FF 128
#define NRBF 20
#define MAXDEG 64
#define PI_OVER_CUT 0.6283185307179586f   // pi / 5.0

typedef _Float16 h8 __attribute__((ext_vector_type(8)));
typedef float    f4 __attribute__((ext_vector_type(4)));

union pk32 { unsigned int u; _Float16 h[2]; };

// ---------------------------------------------------------------------------
__global__ __launch_bounds__(256) void k_zero(int* __restrict__ counts) {
    int i = blockIdx.x * 256 + threadIdx.x;
    if (i < NN) counts[i] = 0;
}

__global__ __launch_bounds__(256) void k_bucket(const int* __restrict__ dst,
                                                int* __restrict__ counts,
                                                int* __restrict__ slots) {
    int e = blockIdx.x * 256 + threadIdx.x;
    if (e < EE) {
        int n = dst[e];
        int slot = atomicAdd(&counts[n], 1);
        if (slot < MAXDEG) slots[n * MAXDEG + slot] = e;
    }
}

// Convert all GEMM weights to f16 once (L2-resident afterwards).
__global__ __launch_bounds__(256) void k_wconv(
    const float* __restrict__ Wu, const float* __restrict__ Wv,
    const float* __restrict__ Wu1, const float* __restrict__ Wu2,
    const float* __restrict__ Wp1, const float* __restrict__ Wp2,
    const float* __restrict__ Ww, const float* __restrict__ bw,
    _Float16* __restrict__ Wuh, _Float16* __restrict__ Wvh,
    _Float16* __restrict__ Wu1h, _Float16* __restrict__ Wu2h,
    _Float16* __restrict__ Wp1h, _Float16* __restrict__ Wp2h,
    _Float16* __restrict__ Wwh32)
{
    int i = blockIdx.x * 256 + threadIdx.x;
    if (i < 16384) { Wuh[i] = (_Float16)Wu[i]; Wvh[i] = (_Float16)Wv[i];
                     Wp1h[i] = (_Float16)Wp1[i]; }
    if (i < 32768) { Wu1h[i] = (_Float16)Wu1[i]; }
    if (i < 49152) { Wu2h[i] = (_Float16)Wu2[i]; Wp2h[i] = (_Float16)Wp2[i]; }
    if (i < 8192) {
        int col = i >> 5, k = i & 31;
        int sr = col < 128 ? col : col + 128;
        _Float16 v = (_Float16)0.f;
        if (k < 20)       v = (_Float16)Ww[sr * NRBF + k];
        else if (k == 20) v = (_Float16)bw[sr];
        Wwh32[i] = v;
    }
}

// ---------------------------------------------------------------------------
// K1 (MFMA): s0 = emb[z]; h1 = silu(Wp1 s + bp1); phi = Wp2 h1 + bp2.
__global__ __launch_bounds__(256) void k_node_phi_mfma(
    const float* __restrict__ emb, const int* __restrict__ z,
    const _Float16* __restrict__ Wp1h, const float* __restrict__ bp1,
    const _Float16* __restrict__ Wp2h, const float* __restrict__ bp2,
    unsigned int* __restrict__ phi_pk, float* __restrict__ s_io)
{
    __shared__ _Float16 Ss[32 * 128];
    __shared__ _Float16 H1s[32 * 128];

    const int t    = threadIdx.x;
    const int lane = t & 63;
    const int w    = t >> 6;
    const int lr   = lane & 15;
    const int lq   = lane >> 4;
    const int n0   = blockIdx.x * 32;
    const f4 z4 = {0.f, 0.f, 0.f, 0.f};

    for (int i = t; i < 512; i += 256) {             // 32 rows x 16 granules
        int n = i >> 4, gr = i & 15;
        int nn = n0 + n; if (nn > NN - 1) nn = NN - 1;
        const float* sp = &emb[(size_t)z[nn] * FF + gr * 8];
        float4 aa = *(const float4*)sp;
        float4 bb = *(const float4*)(sp + 4);
        h8 hv;
        hv[0] = (_Float16)aa.x; hv[1] = (_Float16)aa.y;
        hv[2] = (_Float16)aa.z; hv[3] = (_Float16)aa.w;
        hv[4] = (_Float16)bb.x; hv[5] = (_Float16)bb.y;
        hv[6] = (_Float16)bb.z; hv[7] = (_Float16)bb.w;
        *(h8*)&Ss[(n * 16 + (gr ^ (n & 15))) * 8] = hv;
        float* op = &s_io[(size_t)nn * FF + gr * 8];
        *(float4*)op       = aa;
        *(float4*)(op + 4) = bb;
    }
    __syncthreads();

    f4 acc1[2][2];
    #pragma unroll
    for (int a = 0; a < 2; ++a)
        #pragma unroll
        for (int m = 0; m < 2; ++m) acc1[a][m] = z4;
    {
        const _Float16* bb = Wp1h + (size_t)lr * 128 + lq * 8;
        #pragma unroll
        for (int g2 = 0; g2 < 2; ++g2) {
            h8 bf[4];
            #pragma unroll
            for (int ks = 0; ks < 4; ++ks)
                bf[ks] = *(const h8*)(bb + ((2 * w + g2) * 16) * 128 + ks * 32);
            #pragma unroll
            for (int mt = 0; mt < 2; ++mt) {
                const int r = mt * 16 + lr;
                #pragma unroll
                for (int ks = 0; ks < 4; ++ks) {
                    h8 af = *(const h8*)&Ss[(r * 16 + ((ks * 4 + lq) ^ (r & 15))) * 8];
                    acc1[g2][mt] = __builtin_amdgcn_mfma_f32_16x16x32_f16(
                        af, bf[ks], acc1[g2][mt], 0, 0, 0);
                }
            }
        }
    }
    #pragma unroll
    for (int g2 = 0; g2 < 2; ++g2) {
        const int g = (2 * w + g2) * 16 + lr;
        const float b1 = bp1[g];
        #pragma unroll
        for (int mt = 0; mt < 2; ++mt)
            #pragma unroll
            for (int r = 0; r < 4; ++r) {
                float x = acc1[g2][mt][r] + b1;
                float y = x / (1.f + __expf(-x));
                int n = mt * 16 + lq * 4 + r;
                H1s[(n * 16 + ((g >> 3) ^ (n & 15))) * 8 + (g & 7)] = (_Float16)y;
            }
    }
    __syncthreads();

    f4 accS[2][2], accV[2][2];
    #pragma unroll
    for (int a = 0; a < 2; ++a)
        #pragma unroll
        for (int m = 0; m < 2; ++m) { accS[a][m] = z4; accV[a][m] = z4; }
    {
        const _Float16* bbs = Wp2h + (size_t)lr * 128 + lq * 8;
        const _Float16* bbv = Wp2h + (size_t)(256 + lr) * 128 + lq * 8;
        #pragma unroll
        for (int g2 = 0; g2 < 2; ++g2) {
            h8 bfs[4], bfv[4];
            #pragma unroll
            for (int ks = 0; ks < 4; ++ks) {
                bfs[ks] = *(const h8*)(bbs + ((2 * w + g2) * 16) * 128 + ks * 32);
                bfv[ks] = *(const h8*)(bbv + ((2 * w + g2) * 16) * 128 + ks * 32);
            }
            #pragma unroll
            for (int mt = 0; mt < 2; ++mt) {
                const int r = mt * 16 + lr;
                #pragma unroll
                for (int ks = 0; ks < 4; ++ks) {
                    h8 af = *(const h8*)&H1s[(r * 16 + ((ks * 4 + lq) ^ (r & 15))) * 8];
                    accS[g2][mt] = __builtin_amdgcn_mfma_f32_16x16x32_f16(
                        af, bfs[ks], accS[g2][mt], 0, 0, 0);
                    accV[g2][mt] = __builtin_amdgcn_mfma_f32_16x16x32_f16(
                        af, bfv[ks], accV[g2][mt], 0, 0, 0);
                }
            }
        }
    }
    #pragma unroll
    for (int g2 = 0; g2 < 2; ++g2) {
        const int g = (2 * w + g2) * 16 + lr;
        const float bsa = bp2[g], bva = bp2[256 + g];
        #pragma unroll
        for (int mt = 0; mt < 2; ++mt)
            #pragma unroll
            for (int r = 0; r < 4; ++r) {
                int n = mt * 16 + lq * 4 + r;
                int nn = n0 + n;
                if (nn < NN) {
                    pk32 pk;
                    pk.h[0] = (_Float16)(accS[g2][mt][r] + bsa);
                    pk.h[1] = (_Float16)(accV[g2][mt][r] + bva);
                    phi_pk[(size_t)nn * FF + g] = pk.u;
                }
            }
    }
}

// ---------------------------------------------------------------------------
// K2 (MFMA Wf): per destination node. v-messages go ONLY to xg (f16);
// v_io is no longer written here (k_update reconstructs the residual from
// its staged f16 copy). s_io keeps the f32 += (read is L3-hot).
__global__ __launch_bounds__(128) void k_edge_mfma(
    const float* __restrict__ pos,
    const _Float16* __restrict__ Wwh32,
    const int* __restrict__ src,
    const int* __restrict__ counts, const int* __restrict__ slots,
    const unsigned int* __restrict__ phi_pk,
    float* __restrict__ s_io,
    _Float16* __restrict__ xg)
{
    __shared__ _Float16 A[16 * 32];          // swizzled rbf A-tile (1 KB)
    __shared__ float dirs[16][4];            // ux, uy, uz, asfloat(sI)
    __shared__ float dls[16];                // distance per edge
    __shared__ unsigned int wf[16 * 130];    // interleaved {s,v} f16 Wf (8.3 KB)

    const int t    = threadIdx.x;
    const int lane = t & 63;
    const int w    = t >> 6;     // wave 0 = s-half, wave 1 = v-half
    const int lr   = lane & 15;
    const int lq   = lane >> 4;
    const int n    = blockIdx.x;
    const f4 z4 = {0.f, 0.f, 0.f, 0.f};

    // B-fragments: tile-invariant, loaded once (L2-hot).
    h8 bf[8];
    #pragma unroll
    for (int j = 0; j < 8; ++j)
        bf[j] = *(const h8*)&Wwh32[(size_t)((w * 8 + j) * 16 + lr) * 32 + lq * 8];

    const float px = pos[3 * n], py = pos[3 * n + 1], pz = pos[3 * n + 2];

    int deg = counts[n];
    deg = deg > MAXDEG ? MAXDEG : deg;

    float acc_s = 0.f, av0 = 0.f, av1 = 0.f, av2 = 0.f;

    for (int t0 = 0; t0 < deg; t0 += 16) {
        const int degT = (deg - t0) < 16 ? (deg - t0) : 16;
        __syncthreads();                       // guard LDS reuse
        // ---- phase 1: per-edge geometry (threads 0..degT-1) ----
        if (t < degT) {
            int e  = slots[n * MAXDEG + t0 + t];
            int sI = src[e];
            float rx = px - pos[3 * sI];
            float ry = py - pos[3 * sI + 1];
            float rz = pz - pos[3 * sI + 2];
            float d = sqrtf(rx * rx + ry * ry + rz * rz);
            d = fmaxf(d, 1e-9f);
            float di = 1.f / d;
            dirs[t][0] = rx * di;
            dirs[t][1] = ry * di;
            dirs[t][2] = rz * di;
            dirs[t][3] = __int_as_float(sI);
            dls[t] = d;
        }
        __syncthreads();
        // ---- phase 2: rbf -> A-tile. thread = (edge m = t&15, kk = t>>4) ----
        {
            const int m = t & 15, kk = t >> 4;
            float d  = dls[m];
            float di = 1.f / d;
            float v0 = __sinf((float)(kk + 1) * PI_OVER_CUT * d) * di;
            float v1 = __sinf((float)(kk + 9) * PI_OVER_CUT * d) * di;
            float v2;
            if (kk < 4)       v2 = __sinf((float)(kk + 17) * PI_OVER_CUT * d) * di;
            else if (kk == 4) v2 = 1.0f;     // k=20: bias element
            else              v2 = 0.f;
            // chunk-swizzled store: phys chunk = (k>>3) ^ (m&3)
            #define STO(K, V) A[m * 32 + (((K) >> 3) ^ (m & 3)) * 8 + ((K) & 7)] = (_Float16)(V)
            STO(kk,      v0);
            STO(kk + 8,  v1);
            STO(kk + 16, v2);
            STO(kk + 24, 0.f);
            #undef STO
        }
        __syncthreads();
        // ---- MFMA: Wf tile (each wave: 8 n-tiles of 16 features) ----
        {
            h8 af = *(const h8*)&A[(lr * 4 + (lq ^ (lr & 3))) * 8];
            #pragma unroll
            for (int j = 0; j < 8; ++j) {
                f4 dd = __builtin_amdgcn_mfma_f32_16x16x32_f16(af, bf[j], z4, 0, 0, 0);
                #pragma unroll
                for (int r = 0; r < 4; ++r) {
                    int m = lq * 4 + r;
                    ((_Float16*)&wf[m * 130 + j * 16 + lr])[w] = (_Float16)dd[r];
                }
            }
        }
        __syncthreads();
        // ---- accumulation over this tile's edges ----
        for (int m = 0; m < degT; ++m) {
            float4 dir = *(const float4*)&dirs[m][0];
            int sI = __builtin_amdgcn_readfirstlane(__float_as_int(dir.w));
            pk32 ph, wfu;
            ph.u  = phi_pk[(size_t)sI * FF + t];
            wfu.u = wf[m * 130 + t];
            float ps = (float)ph.h[0] * (float)wfu.h[0];
            float pv = (float)ph.h[1] * (float)wfu.h[1];
            acc_s += ps;
            av0 = fmaf(pv, dir.x, av0);
            av1 = fmaf(pv, dir.y, av1);
            av2 = fmaf(pv, dir.z, av2);
        }
    }

    size_t gi = (size_t)n * FF + t;
    s_io[gi] += acc_s;
    xg[((size_t)n * 3 + 0) * FF + t] = (_Float16)av0;
    xg[((size_t)n * 3 + 1) * FF + t] = (_Float16)av1;
    xg[((size_t)n * 3 + 2) * FF + t] = (_Float16)av2;
}

// ---------------------------------------------------------------------------
// K3: update block on f16 MFMA. Residuals (s, v) are read back from the
// staged f16 LDS tiles (Hs, Xs) — no global v_io fetch, no epilogue load
// stall. v_io is write-only.
__global__ __launch_bounds__(256) void k_update_mfma(
    const _Float16* __restrict__ xg,
    const _Float16* __restrict__ Wuh, const _Float16* __restrict__ Wvh,
    const _Float16* __restrict__ Wu1h, const _Float16* __restrict__ Wu2h,
    const float* __restrict__ bu, const float* __restrict__ bv,
    const float* __restrict__ bu1, const float* __restrict__ bu2,
    float* __restrict__ s_io, float* __restrict__ v_io)
{
    __shared__ _Float16 Xs[96 * 128];    // A for GEMM1: row = c*32+n, k = f
    __shared__ _Float16 Hs[32 * 256];    // A for GEMM2: [s | Vn]
    __shared__ _Float16 H1s[32 * 128];   // A for GEMM3

    const int t    = threadIdx.x;
    const int lane = t & 63;
    const int w    = t >> 6;     // wave 0..3
    const int lr   = lane & 15;  // A-row / B-col within tile
    const int lq   = lane >> 4;  // k-chunk selector
    const int n0   = blockIdx.x * 32;
    const f4 z4 = {0.f, 0.f, 0.f, 0.f};

    for (int i = t; i < 1536; i += 256) {            // 96 rows x 16 granules
        int row = i >> 4, gr = i & 15;
        int n = row & 31, c = row >> 5;
        int nn = n0 + n; if (nn > NN - 1) nn = NN - 1;
        uint4 d = *(const uint4*)&xg[((size_t)nn * 3 + c) * FF + gr * 8];
        *(uint4*)&Xs[(row * 16 + (gr ^ (row & 15))) * 8] = d;
    }
    for (int i = t; i < 512; i += 256) {             // 32 rows x 16 granules
        int n = i >> 4, gr = i & 15;
        int nn = n0 + n; if (nn > NN - 1) nn = NN - 1;
        const float* sp = &s_io[(size_t)nn * FF + gr * 8];
        float4 aa = *(const float4*)sp;
        float4 bb = *(const float4*)(sp + 4);
        h8 hv;
        hv[0] = (_Float16)aa.x; hv[1] = (_Float16)aa.y;
        hv[2] = (_Float16)aa.z; hv[3] = (_Float16)aa.w;
        hv[4] = (_Float16)bb.x; hv[5] = (_Float16)bb.y;
        hv[6] = (_Float16)bb.z; hv[7] = (_Float16)bb.w;
        *(h8*)&Hs[(n * 32 + (gr ^ (n & 15))) * 8] = hv;
    }
    __syncthreads();

    f4 accU[2][6], accV[2][6];   // [g-subtile][mt = c*2+p]
    #pragma unroll
    for (int a = 0; a < 2; ++a)
        #pragma unroll
        for (int m = 0; m < 6; ++m) { accU[a][m] = z4; accV[a][m] = z4; }

    {   // U pass
        const _Float16* bb = Wuh + (size_t)lr * 128 + lq * 8;
        h8 bfr[2][4];
        #pragma unroll
        for (int g2 = 0; g2 < 2; ++g2)
            #pragma unroll
            for (int ks = 0; ks < 4; ++ks)
                bfr[g2][ks] = *(const h8*)(bb + ((2 * w + g2) * 16) * 128 + ks * 32);
        #pragma unroll
        for (int mt = 0; mt < 6; ++mt) {
            const int r = mt * 16 + lr;
            h8 af[4];
            #pragma unroll
            for (int ks = 0; ks < 4; ++ks)
                af[ks] = *(const h8*)&Xs[(r * 16 + ((ks * 4 + lq) ^ (r & 15))) * 8];
            #pragma unroll
            for (int g2 = 0; g2 < 2; ++g2)
                #pragma unroll
                for (int ks = 0; ks < 4; ++ks)
                    accU[g2][mt] = __builtin_amdgcn_mfma_f32_16x16x32_f16(
                        af[ks], bfr[g2][ks], accU[g2][mt], 0, 0, 0);
        }
    }
    {   // V pass
        const _Float16* bb = Wvh + (size_t)lr * 128 + lq * 8;
        h8 bfr[2][4];
        #pragma unroll
        for (int g2 = 0; g2 < 2; ++g2)
            #pragma unroll
            for (int ks = 0; ks < 4; ++ks)
                bfr[g2][ks] = *(const h8*)(bb + ((2 * w + g2) * 16) * 128 + ks * 32);
        #pragma unroll
        for (int mt = 0; mt < 6; ++mt) {
            const int r = mt * 16 + lr;
            h8 af[4];
            #pragma unroll
            for (int ks = 0; ks < 4; ++ks)
                af[ks] = *(const h8*)&Xs[(r * 16 + ((ks * 4 + lq) ^ (r & 15))) * 8];
            #pragma unroll
            for (int g2 = 0; g2 < 2; ++g2)
                #pragma unroll
                for (int ks = 0; ks < 4; ++ks)
                    accV[g2][mt] = __builtin_amdgcn_mfma_f32_16x16x32_f16(
                        af[ks], bfr[g2][ks], accV[g2][mt], 0, 0, 0);
        }
    }

    float uvr[2][2][4];
    #pragma unroll
    for (int g2 = 0; g2 < 2; ++g2) {
        const int g = (2 * w + g2) * 16 + lr;
        const float bU = bu[g], bV = bv[g];
        #pragma unroll
        for (int p = 0; p < 2; ++p) {
            #pragma unroll
            for (int r = 0; r < 4; ++r) {
                float Ux = accU[g2][0 + p][r] + bU;
                float Uy = accU[g2][2 + p][r] + bU;
                float Uz = accU[g2][4 + p][r] + bU;
                float Vx = accV[g2][0 + p][r] + bV;
                float Vy = accV[g2][2 + p][r] + bV;
                float Vz = accV[g2][4 + p][r] + bV;
                accU[g2][0 + p][r] = Ux;
                accU[g2][2 + p][r] = Uy;
                accU[g2][4 + p][r] = Uz;
                uvr[g2][p][r] = Ux * Vx + Uy * Vy + Uz * Vz;
                float vn = sqrtf(Vx * Vx + Vy * Vy + Vz * Vz);
                int n = p * 16 + lq * 4 + r;
                int gr = 16 + (g >> 3);
                Hs[(n * 32 + (gr ^ (n & 15))) * 8 + (g & 7)] = (_Float16)vn;
            }
        }
    }
    __syncthreads();

    f4 acc2[2][2];
    #pragma unroll
    for (int a = 0; a < 2; ++a)
        #pragma unroll
        for (int m = 0; m < 2; ++m) acc2[a][m] = z4;
    {
        const _Float16* bb = Wu1h + (size_t)lr * 256 + lq * 8;
        #pragma unroll
        for (int g2 = 0; g2 < 2; ++g2) {
            h8 bfr[8];
            #pragma unroll
            for (int ks = 0; ks < 8; ++ks)
                bfr[ks] = *(const h8*)(bb + ((2 * w + g2) * 16) * 256 + ks * 32);
            #pragma unroll
            for (int mt = 0; mt < 2; ++mt) {
                const int r = mt * 16 + lr;
                #pragma unroll
                for (int ks = 0; ks < 8; ++ks) {
                    h8 af = *(const h8*)&Hs[(r * 32 + ((ks * 4 + lq) ^ (r & 15))) * 8];
                    acc2[g2][mt] = __builtin_amdgcn_mfma_f32_16x16x32_f16(
                        af, bfr[ks], acc2[g2][mt], 0, 0, 0);
                }
            }
        }
    }
    #pragma unroll
    for (int g2 = 0; g2 < 2; ++g2) {
        const int g = (2 * w + g2) * 16 + lr;
        const float b1 = bu1[g];
        #pragma unroll
        for (int mt = 0; mt < 2; ++mt)
            #pragma unroll
            for (int r = 0; r < 4; ++r) {
                float x = acc2[g2][mt][r] + b1;
                float y = x / (1.f + __expf(-x));
                int n = mt * 16 + lq * 4 + r;
                int gr = g >> 3;
                H1s[(n * 16 + (gr ^ (n & 15))) * 8 + (g & 7)] = (_Float16)y;
            }
    }
    __syncthreads();

    f4 acc3[3][2][2];
    #pragma unroll
    for (int a = 0; a < 3; ++a)
        #pragma unroll
        for (int b = 0; b < 2; ++b)
            #pragma unroll
            for (int m = 0; m < 2; ++m) acc3[a][b][m] = z4;
    {
        const _Float16* bb = Wu2h + (size_t)lr * 128 + lq * 8;
        #pragma unroll
        for (int ai = 0; ai < 3; ++ai)
            #pragma unroll
            for (int g2 = 0; g2 < 2; ++g2) {
                const int jt = ai * 8 + 2 * w + g2;
                h8 bfr[4];
                #pragma unroll
                for (int ks = 0; ks < 4; ++ks)
                    bfr[ks] = *(const h8*)(bb + (size_t)(jt * 16) * 128 + ks * 32);
                #pragma unroll
                for (int mt = 0; mt < 2; ++mt) {
                    const int r = mt * 16 + lr;
                    #pragma unroll
                    for (int ks = 0; ks < 4; ++ks) {
                        h8 af = *(const h8*)&H1s[(r * 16 + ((ks * 4 + lq) ^ (r & 15))) * 8];
                        acc3[ai][g2][mt] = __builtin_amdgcn_mfma_f32_16x16x32_f16(
                            af, bfr[ks], acc3[ai][g2][mt], 0, 0, 0);
                    }
                }
            }
    }

    // ---- final epilogue: residuals from staged f16 LDS tiles ----
    #pragma unroll
    for (int g2 = 0; g2 < 2; ++g2) {
        const int g = (2 * w + g2) * 16 + lr;
        const float b1 = bu2[g], b2 = bu2[128 + g], b3 = bu2[256 + g];
        #pragma unroll
        for (int p = 0; p < 2; ++p)
            #pragma unroll
            for (int r = 0; r < 4; ++r) {
                int n = p * 16 + lq * 4 + r;
                int nn = n0 + n;
                if (nn < NN) {
                    float a1 = acc3[0][g2][p][r] + b1;
                    float a2 = acc3[1][g2][p][r] + b2;
                    float a3 = acc3[2][g2][p][r] + b3;
                    size_t gi = (size_t)nn * FF + g;
                    // s residual from Hs (cols 0:128), v residual from Xs
                    float s1 = (float)Hs[(n * 32 + ((g >> 3) ^ (n & 15))) * 8 + (g & 7)];
                    s_io[gi] = s1 + a2 + uvr[g2][p][r] * a3;
                    float vx = (float)Xs[((0 * 32 + n) * 16 + ((g >> 3) ^ (n & 15))) * 8 + (g & 7)];
                    float vy = (float)Xs[((1 * 32 + n) * 16 + ((g >> 3) ^ (n & 15))) * 8 + (g & 7)];
                    float vz = (float)Xs[((2 * 32 + n) * 16 + ((g >> 3) ^ (n & 15))) * 8 + (g & 7)];
                    v_io[gi * 3 + 0] = vx + accU[g2][0 + p][r] * a1;
                    v_io[gi * 3 + 1] = vy + accU[g2][2 + p][r] * a1;
                    v_io[gi * 3 + 2] = vz + accU[g2][4 + p][r] * a1;
                }
            }
    }
}

// ---------------------------------------------------------------------------
extern "C" void kernel_launch(void* const* d_in, const int* in_sizes, int n_in,
                              void* d_out, int out_size, void* d_ws, size_t ws_size,
                              hipStream_t stream)
{
    const float* pos = (const float*)d_in[0];
    const float* emb = (const float*)d_in[1];
    const float* Wp1 = (const float*)d_in[2];
    const float* bp1 = (const float*)d_in[3];
    const float* Wp2 = (const float*)d_in[4];
    const float* bp2 = (const float*)d_in[5];
    const float* Ww  = (const float*)d_in[6];
    const float* bw  = (const float*)d_in[7];
    const float* Wu  = (const float*)d_in[8];
    const float* bu  = (const float*)d_in[9];
    const float* Wv  = (const float*)d_in[10];
    const float* bv  = (const float*)d_in[11];
    const float* Wu1 = (const float*)d_in[12];
    const float* bu1 = (const float*)d_in[13];
    const float* Wu2 = (const float*)d_in[14];
    const float* bu2 = (const float*)d_in[15];
    const int* z   = (const int*)d_in[16];
    const int* src = (const int*)d_in[17];
    const int* dst = (const int*)d_in[18];

    float* s_io = (float*)d_out;
    float* v_io = (float*)d_out + (size_t)NN * FF;

    char* ws = (char*)d_ws;
    unsigned int* phi_pk = (unsigned int*)ws;            // NN*FF uints
    _Float16* xg    = (_Float16*)(phi_pk + (size_t)NN * FF);  // NN*3*FF
    _Float16* Wuh   = xg + (size_t)NN * 3 * FF;
    _Float16* Wvh   = Wuh  + 128 * 128;
    _Float16* Wu1h  = Wvh  + 128 * 128;
    _Float16* Wu2h  = Wu1h + 128 * 256;
    _Float16* Wp1h  = Wu2h + 384 * 128;
    _Float16* Wp2h  = Wp1h + 128 * 128;
    _Float16* Wwh32 = Wp2h + 384 * 128;                  // 256*32
    int* counts = (int*)(Wwh32 + 256 * 32);
    int* slots  = counts + NN;

    k_zero  <<<(NN + 255) / 256, 256, 0, stream>>>(counts);
    k_bucket<<<(EE + 255) / 256, 256, 0, stream>>>(dst, counts, slots);
    k_wconv <<<192, 256, 0, stream>>>(Wu, Wv, Wu1, Wu2, Wp1, Wp2, Ww, bw,
                                      Wuh, Wvh, Wu1h, Wu2h, Wp1h, Wp2h, Wwh32);
    k_node_phi_mfma<<<(NN + 31) / 32, 256, 0, stream>>>(emb, z, Wp1h, bp1,
                                                        Wp2h, bp2,
                                                        phi_pk, s_io);
    k_edge_mfma<<<NN, 128, 0, stream>>>(pos, Wwh32, src, counts, slots,
                                        phi_pk, s_io, xg);
    k_update_mfma<<<(NN + 31) / 32, 256, 0, stream>>>(xg, Wuh, Wvh, Wu1h, Wu2h,
                                                      bu, bv, bu1, bu2, s_io, v_io);
}